// Round 10
// baseline (153.962 us; speedup 1.0000x reference)
//
#include <hip/hip_runtime.h>

#define B_    512

static constexpr float TINYF = 1.17549435e-38f;
typedef float fx4  __attribute__((ext_vector_type(4)));
typedef short bf16x8 __attribute__((ext_vector_type(8)));
typedef float f32x4 __attribute__((ext_vector_type(4)));
typedef unsigned short u16x4 __attribute__((ext_vector_type(4)));

// Contraction-pinned fp32 ops (RN, no fma fusion possible across these).
__device__ __forceinline__ float fmul_s(float a, float b) { float r; asm("v_mul_f32 %0, %1, %2" : "=v"(r) : "v"(a), "v"(b)); return r; }
__device__ __forceinline__ float fadd_s(float a, float b) { float r; asm("v_add_f32 %0, %1, %2" : "=v"(r) : "v"(a), "v"(b)); return r; }
__device__ __forceinline__ float fsub_s(float a, float b) { float r; asm("v_sub_f32 %0, %1, %2" : "=v"(r) : "v"(a), "v"(b)); return r; }

// ---------------------------------------------------------------------------
// Threefry-2x32, key = (0, 42), partitionable path.
// ---------------------------------------------------------------------------
__device__ __forceinline__ unsigned tf_bits(unsigned lo) {
  const unsigned ks0 = 0u, ks1 = 42u, ks2 = 0x1BD11BF0u;
  unsigned x0 = 0u + ks0;
  unsigned x1 = lo + ks1;
#define TFR(r) { x0 += x1; x1 = (x1 << r) | (x1 >> (32 - r)); x1 ^= x0; }
  TFR(13) TFR(15) TFR(26) TFR(6)
  x0 += ks1; x1 += ks2 + 1u;
  TFR(17) TFR(29) TFR(16) TFR(24)
  x0 += ks2; x1 += ks0 + 2u;
  TFR(13) TFR(15) TFR(26) TFR(6)
  x0 += ks0; x1 += ks1 + 3u;
  TFR(17) TFR(29) TFR(16) TFR(24)
  x0 += ks1; x1 += ks2 + 4u;
  TFR(13) TFR(15) TFR(26) TFR(6)
  x0 += ks2; x1 += ks0 + 5u;
#undef TFR
  return x0 ^ x1;
}

// Exact fp32 -> 3x bf16 split (truncation)
__device__ __forceinline__ void split3(float v, unsigned& b1, unsigned& b2, unsigned& b3) {
  unsigned u1 = __float_as_uint(v) & 0xFFFF0000u;
  float r1 = v - __uint_as_float(u1);
  unsigned u2 = __float_as_uint(r1) & 0xFFFF0000u;
  float r2 = r1 - __uint_as_float(u2);
  unsigned u3 = __float_as_uint(r2) & 0xFFFF0000u;
  b1 = u1 >> 16; b2 = u2 >> 16; b3 = u3 >> 16;
}

__device__ __forceinline__ unsigned short planeOf(float v, int s) {
  unsigned u1 = __float_as_uint(v) & 0xFFFF0000u;
  if (s == 0) return (unsigned short)(u1 >> 16);
  float r1 = v - __uint_as_float(u1);
  unsigned u2 = __float_as_uint(r1) & 0xFFFF0000u;
  if (s == 1) return (unsigned short)(u2 >> 16);
  float r2 = r1 - __uint_as_float(u2);
  return (unsigned short)((__float_as_uint(r2) & 0xFFFF0000u) >> 16);
}

// 6-product split accumulation (drops terms <= 2^-27 relative)
#define MF6(A0, A1, A2, Bv0, Bv1, Bv2, ACC)                                   \
  ACC = __builtin_amdgcn_mfma_f32_16x16x32_bf16(A0, Bv0, ACC, 0, 0, 0);       \
  ACC = __builtin_amdgcn_mfma_f32_16x16x32_bf16(A0, Bv1, ACC, 0, 0, 0);       \
  ACC = __builtin_amdgcn_mfma_f32_16x16x32_bf16(A1, Bv0, ACC, 0, 0, 0);       \
  ACC = __builtin_amdgcn_mfma_f32_16x16x32_bf16(A0, Bv2, ACC, 0, 0, 0);       \
  ACC = __builtin_amdgcn_mfma_f32_16x16x32_bf16(A1, Bv1, ACC, 0, 0, 0);       \
  ACC = __builtin_amdgcn_mfma_f32_16x16x32_bf16(A2, Bv0, ACC, 0, 0, 0);

// ---------------------------------------------------------------------------
// Setup: W1/W2 split planes, centroid norms, centroid split planes.
// ---------------------------------------------------------------------------
__global__ void k_setup(const float* __restrict__ W1, const float* __restrict__ W2,
                        const float* __restrict__ cen,
                        unsigned short* __restrict__ Wg1, unsigned short* __restrict__ Wg2,
                        unsigned short* __restrict__ cen3, float* __restrict__ ccbuf) {
  int bi = blockIdx.x, tid = threadIdx.x;
  if (bi < 144) {
    const float* W; unsigned short* Wg; int nk, s, ks, g;
    if (bi < 48) { W = W1; Wg = Wg1; nk = 4; s = bi >> 4; ks = (bi >> 2) & 3; g = bi & 3; }
    else { int t = bi - 48; W = W2; Wg = Wg2; nk = 8; s = t >> 5; ks = (t >> 2) & 7; g = t & 3; }
    int n = tid;
    bf16x8 hv;
#pragma unroll
    for (int jj = 0; jj < 8; ++jj) {
      float v = W[(size_t)(ks * 32 + g * 8 + jj) * 256 + n];
      hv[jj] = (short)planeOf(v, s);
    }
    *(bf16x8*)&Wg[((((size_t)s * nk + ks) * 4 + g) * 256 + n) * 8] = hv;
  } else if (bi == 144) {
    int k = tid >> 3, l8 = tid & 7;
    float s = 0.0f;
    for (int m = 0; m < 32; ++m) { float v = cen[k * 256 + l8 + 8 * m]; s += v * v; }
#pragma unroll
    for (int d = 1; d < 8; d <<= 1) s += __shfl_xor(s, d, 64);
    if (l8 == 0) ccbuf[k] = s;
  } else {
    int s = bi - 145;
    for (int u = 0; u < 4; ++u) {
      int idx = tid + 256 * u;
      int ks = idx >> 7, c = (idx >> 6) & 1, rem = idx & 63;
      int l15v = rem >> 2, lgv = rem & 3;
      bf16x8 hv;
#pragma unroll
      for (int jj = 0; jj < 8; ++jj)
        hv[jj] = (short)planeOf(cen[(size_t)(16 * c + l15v) * 256 + 32 * ks + 8 * lgv + jj], s);
      *(bf16x8*)&cen3[(size_t)s * 8192 + (size_t)idx * 8] = hv;
    }
  }
}

// ---------------------------------------------------------------------------
// Layer core (global->global): out = relu(maskS * (Ahat @ (A @ W) + biaS)).
// ---------------------------------------------------------------------------
__device__ __forceinline__ void layer_core(const float* __restrict__ A,
                                           const unsigned short* __restrict__ Wg,
                                           const unsigned short* AhP,
                                           const float* biaS, const float* maskS,
                                           float* __restrict__ out, int nk,
                                           char* U, int b, int tid) {
  unsigned short (*Ap)[3][2112] = (unsigned short(*)[3][2112])U;  // [2][3][2112]
  unsigned short (*Tbuf)[72]    = (unsigned short(*)[72])U;       // [256][72]
  int w = tid >> 6, l = tid & 63;
  int l15 = l & 15, lg = l >> 4;
  int K = nk * 32;
  int srow = tid >> 2, sg = tid & 3;
  const float* sp = A + (size_t)srow * K + sg * 8;

  // stage K-step 0 into buffer 0
  {
    float4 v0 = *(const float4*)(sp);
    float4 v1 = *(const float4*)(sp + 4);
    float vv[8] = {v0.x, v0.y, v0.z, v0.w, v1.x, v1.y, v1.z, v1.w};
    bf16x8 p1, p2, p3;
#pragma unroll
    for (int jj = 0; jj < 8; ++jj) {
      unsigned h1, h2, h3; split3(vv[jj], h1, h2, h3);
      p1[jj] = (short)h1; p2[jj] = (short)h2; p3[jj] = (short)h3;
    }
    int off = sg * 528 + srow * 8;
    *(bf16x8*)&Ap[0][0][off] = p1;
    *(bf16x8*)&Ap[0][1][off] = p2;
    *(bf16x8*)&Ap[0][2][off] = p3;
  }
  __syncthreads();

  f32x4 acc1[4][4];
#pragma unroll
  for (int q = 0; q < 4; ++q)
#pragma unroll
    for (int c = 0; c < 4; ++c) acc1[q][c] = (f32x4){0.f, 0.f, 0.f, 0.f};

  const size_t wss = (size_t)nk * 8192;

  for (int ks = 0; ks < nk; ++ks) {
    int cur = ks & 1;
    float4 v0, v1;
    bool pf = (ks + 1 < nk);
    if (pf) {
      v0 = *(const float4*)(sp + (ks + 1) * 32);
      v1 = *(const float4*)(sp + (ks + 1) * 32 + 4);
    }
    bf16x8 af[4][3];
#pragma unroll
    for (int q = 0; q < 4; ++q) {
      int off = lg * 528 + (16 * q + l15) * 8;
#pragma unroll
      for (int s = 0; s < 3; ++s) af[q][s] = *(const bf16x8*)&Ap[cur][s][off];
    }
#pragma unroll
    for (int c = 0; c < 4; ++c) {
      size_t wbase = (((size_t)ks * 4 + lg) * 256 + (64 * w + 16 * c + l15)) * 8;
      bf16x8 b0 = *(const bf16x8*)&Wg[wbase];
      bf16x8 b1 = *(const bf16x8*)&Wg[wbase + wss];
      bf16x8 b2 = *(const bf16x8*)&Wg[wbase + 2 * wss];
#pragma unroll
      for (int q = 0; q < 4; ++q) {
        MF6(af[q][0], af[q][1], af[q][2], b0, b1, b2, acc1[q][c]);
      }
    }
    if (pf) {
      float vv[8] = {v0.x, v0.y, v0.z, v0.w, v1.x, v1.y, v1.z, v1.w};
      bf16x8 p1, p2, p3;
#pragma unroll
      for (int jj = 0; jj < 8; ++jj) {
        unsigned h1, h2, h3; split3(vv[jj], h1, h2, h3);
        p1[jj] = (short)h1; p2[jj] = (short)h2; p3[jj] = (short)h3;
      }
      int off = sg * 528 + srow * 8;
      *(bf16x8*)&Ap[cur ^ 1][0][off] = p1;
      *(bf16x8*)&Ap[cur ^ 1][1][off] = p2;
      *(bf16x8*)&Ap[cur ^ 1][2][off] = p3;
    }
    __syncthreads();
  }

  // GEMM#2 phased over T split-planes sB; product budget nA = 3 - sB.
  f32x4 acc2[4][4];
#pragma unroll
  for (int q = 0; q < 4; ++q)
#pragma unroll
    for (int c = 0; c < 4; ++c) acc2[q][c] = (f32x4){0.f, 0.f, 0.f, 0.f};

#pragma unroll
  for (int sB = 0; sB < 3; ++sB) {
    const int nA = 3 - sB;
    __syncthreads();
#pragma unroll
    for (int q = 0; q < 4; ++q)
#pragma unroll
      for (int c = 0; c < 4; ++c) {
        u16x4 pv;
#pragma unroll
        for (int r = 0; r < 4; ++r) pv[r] = planeOf(acc1[q][c][r], sB);
        *(u16x4*)&Tbuf[64 * w + 16 * c + l15][16 * q + 4 * lg] = pv;
      }
    __syncthreads();
#pragma unroll
    for (int mt = 0; mt < 2; ++mt) {
      bf16x8 bf[4];
#pragma unroll
      for (int c = 0; c < 4; ++c)
        bf[c] = *(const bf16x8*)&Tbuf[64 * w + 16 * c + l15][32 * mt + 8 * lg];
#pragma unroll
      for (int q2 = 0; q2 < 4; ++q2) {
        bf16x8 afr[3];
#pragma unroll
        for (int sA = 0; sA < 3; ++sA)
          if (sA < nA)
            afr[sA] = *(const bf16x8*)&AhP[((((size_t)(sA * 2 + mt) * 4 + q2) * 4 + lg) * 16 + l15) * 8];
#pragma unroll
        for (int c = 0; c < 4; ++c)
#pragma unroll
          for (int sA = 0; sA < 3; ++sA)
            if (sA < nA)
              acc2[q2][c] = __builtin_amdgcn_mfma_f32_16x16x32_bf16(afr[sA], bf[c], acc2[q2][c], 0, 0, 0);
      }
    }
  }

  // epilogue: (acc + bias) * mask, relu -> global
#pragma unroll
  for (int q2 = 0; q2 < 4; ++q2) {
#pragma unroll
    for (int c = 0; c < 4; ++c) {
      int n = 64 * w + 16 * c + l15;
      float bv = biaS[n];
#pragma unroll
      for (int r = 0; r < 4; ++r) {
        int row = 16 * q2 + 4 * lg + r;
        float val = (acc2[q2][c][r] + bv) * maskS[row];
        out[((size_t)b * 64 + row) * 256 + n] = fmaxf(val, 0.0f);
      }
    }
  }
}

// ---------------------------------------------------------------------------
// Fused prep + layer1 + layer2.  63 KB LDS -> 2 blocks/CU.
// ---------------------------------------------------------------------------
__global__ __launch_bounds__(256, 2) void k_fused(
    const float* __restrict__ x, const float* __restrict__ adj,
    const void* __restrict__ mp,
    const float* __restrict__ b1v, const float* __restrict__ b2v,
    const unsigned short* __restrict__ Wg1, const unsigned short* __restrict__ Wg2,
    unsigned long long* __restrict__ nbr, float* __restrict__ maskf,
    float* __restrict__ bufA, float* __restrict__ bufB) {
  __shared__ unsigned short AhP[12288];      // 24.6 KB
  __shared__ float biaS[256];
  __shared__ float maskS[64];
  __shared__ int s_ni, s_nf;
  __shared__ __align__(16) char U[36864];    // union: prep 33.3K / layers 36.9K

  int b = blockIdx.x, tid = threadIdx.x;

  // ===== phase 0: prep =====
  {
    float* adjS = (float*)U;
    float (*AhS)[65] = (float(*)[65])(U + 16384);
    float* dis = (float*)(U + 33024);
    if (tid == 0) { s_ni = 0; s_nf = 0; }
    const float* ab = adj + (size_t)b * 4096;
    for (int i = tid; i < 4096; i += 256) adjS[i] = ab[i];
    {
      const unsigned* wp = (const unsigned*)mp;
      int ni = 0, nf = 0;
      for (int i = tid; i < 2048; i += 256) {
        unsigned v = wp[i];
        if (v > 1u) ni = 1;
        if (v != 0u && v != 0x3f800000u) nf = 1;
      }
      if (ni) atomicOr(&s_ni, 1);
      if (nf) atomicOr(&s_nf, 1);
    }
    biaS[tid] = b1v[tid];
    __syncthreads();
    if (tid < 64) {
      float s = 0.0f;
      unsigned long long m = 0ull;
      for (int j = 0; j < 64; ++j) {
        float v = adjS[j * 64 + tid];          // symmetric
        s += (j == tid) ? (v + 1.0f) : v;
        if (v != 0.0f) m |= (1ull << j);
      }
      dis[tid] = 1.0f / sqrtf(fmaxf(s, 1.0f));
      nbr[b * 64 + tid] = m;
      int fl = s_ni ? (s_nf ? 2 : 1) : 0;
      int i = b * 64 + tid;
      float r;
      if (fl == 0)      r = ((const int*)mp)[i] ? 1.0f : 0.0f;
      else if (fl == 1) r = (((const float*)mp)[i] != 0.0f) ? 1.0f : 0.0f;
      else              r = ((const unsigned char*)mp)[i] ? 1.0f : 0.0f;
      maskS[tid] = r;
      maskf[i] = r;
    }
    __syncthreads();
    for (int i = tid; i < 4096; i += 256) {
      int r = i >> 6, c = i & 63;
      float a = adjS[i] + ((r == c) ? 1.0f : 0.0f);
      AhS[r][c] = (dis[r] * a) * dis[c];
    }
    __syncthreads();
    for (int ch = tid; ch < 1536; ch += 256) {
      int l15v = ch & 15, lgv = (ch >> 4) & 3, q2 = (ch >> 6) & 3, mt = (ch >> 8) & 1, s = ch >> 9;
      bf16x8 hv;
#pragma unroll
      for (int jj = 0; jj < 8; ++jj)
        hv[jj] = (short)planeOf(AhS[16 * q2 + l15v][32 * mt + 8 * lgv + jj], s);
      *(bf16x8*)&AhP[(size_t)ch * 8] = hv;
    }
    __syncthreads();
  }

  // ===== phase 1: layer1 (x -> bufA) =====
  layer_core(x + (size_t)b * 64 * 128, Wg1, AhP, biaS, maskS, bufA, 4, U, b, tid);
  __syncthreads();
  biaS[tid] = b2v[tid];

  // ===== phase 2: layer2 (bufA -> bufB) =====
  layer_core(bufA + (size_t)b * 64 * 256, Wg2, AhP, biaS, maskS, bufB, 8, U, b, tid);
}

// ---------------------------------------------------------------------------
// cdist + softmin + Gumbel-max sampling.  Wave w owns rows 16w..16w+15 with
// full-K GEMM (4 ks-pair accumulators recombined (P0+P1)+(P2+P3) == old Dred
// tree -> bit-exact).  All phases wave-local: ZERO barriers, 9.2 KB LDS.
// ---------------------------------------------------------------------------
__global__ __launch_bounds__(256, 4) void k_cd(const float* __restrict__ h,
                                               const unsigned short* __restrict__ cen3,
                                               const float* __restrict__ ccbuf,
                                               int* __restrict__ conc,
                                               float* __restrict__ pp) {
  __shared__ float lgpS[4][16][33];    // 8448 B
  __shared__ float hhS[64];
  __shared__ float mxS[64], ldS[64];

  int b = blockIdx.x, tid = threadIdx.x;
  int w = tid >> 6, l = tid & 63, l15 = l & 15, lg = l >> 4;
  const float* hb = h + (size_t)b * 16384;

  // hh: lane handles row 16w + (l>>2), quarter q = l&3 (same serial chain as
  // old hhp), then (q0+q1)+(q2+q3) via commutative shfl pairs.
  {
    int row = 16 * w + (l >> 2), q = l & 3;
    float s = 0.0f;
    for (int u = 0; u < 16; ++u) {
      float4 v = *(const float4*)&hb[row * 256 + q * 64 + u * 4];
      float t = fadd_s(fadd_s(fadd_s(fmul_s(v.x, v.x), fmul_s(v.y, v.y)), fmul_s(v.z, v.z)), fmul_s(v.w, v.w));
      s = fadd_s(s, t);
    }
    float s1 = fadd_s(s, __shfl_xor(s, 1, 64));
    float s2 = fadd_s(s1, __shfl_xor(s1, 2, 64));
    if (q == 0) hhS[row] = s2;
  }

  // GEMM: rows 16w+l15, full K, 4 ks-pair partial accumulators.
  f32x4 accP[4][2];
#pragma unroll
  for (int p = 0; p < 4; ++p)
#pragma unroll
    for (int c = 0; c < 2; ++c) accP[p][c] = (f32x4){0.f, 0.f, 0.f, 0.f};

  int arow = 16 * w + l15;
#pragma unroll
  for (int p = 0; p < 4; ++p) {
#pragma unroll
    for (int ks2 = 0; ks2 < 2; ++ks2) {
      int ks = 2 * p + ks2;
      float4 v0 = *(const float4*)&hb[arow * 256 + 32 * ks + 8 * lg];
      float4 v1 = *(const float4*)&hb[arow * 256 + 32 * ks + 8 * lg + 4];
      float vv[8] = {v0.x, v0.y, v0.z, v0.w, v1.x, v1.y, v1.z, v1.w};
      bf16x8 a0, a1, a2;
#pragma unroll
      for (int jj = 0; jj < 8; ++jj) {
        unsigned h1, h2, h3; split3(vv[jj], h1, h2, h3);
        a0[jj] = (short)h1; a1[jj] = (short)h2; a2[jj] = (short)h3;
      }
#pragma unroll
      for (int c = 0; c < 2; ++c) {
        const unsigned short* cb = cen3 + ((size_t)(ks * 2 + c) * 64 + l15 * 4 + lg) * 8;
        bf16x8 b0 = *(const bf16x8*)cb;
        bf16x8 b1 = *(const bf16x8*)(cb + 8192);
        bf16x8 b2 = *(const bf16x8*)(cb + 16384);
        MF6(a0, a1, a2, b0, b1, b2, accP[p][c]);
      }
    }
  }

  // logits for (node = 16w + 4lg + r, k = 16c + l15)
#pragma unroll
  for (int c = 0; c < 2; ++c) {
    int k = 16 * c + l15;
    float cc = ccbuf[k];
#pragma unroll
    for (int r = 0; r < 4; ++r) {
      int rr = 4 * lg + r;
      float dotv = fadd_s(fadd_s(accP[0][c][r], accP[1][c][r]),
                          fadd_s(accP[2][c][r], accP[3][c][r]));
      float hh = hhS[16 * w + rr];
      float d2 = fsub_s(fadd_s(hh, cc), fmul_s(2.0f, dotv));
      lgpS[w][rr][k] = -10.0f * sqrtf(fmaxf(d2, 1e-12f));
    }
  }

  // softmax params: lanes 0-15 of each wave, one row each (same serial order)
  if (l < 16) {
    float mx = -1e30f;
    for (int k = 0; k < 32; ++k) mx = fmaxf(mx, lgpS[w][l][k]);
    float den = 0.0f;
    for (int k = 0; k < 32; ++k) den += expf(lgpS[w][l][k] - mx);
    mxS[16 * w + l] = mx; ldS[16 * w + l] = logf(den);
  }
  // logp
  for (int p4 = l; p4 < 512; p4 += 64) {
    int rr = p4 >> 5, k = p4 & 31;
    lgpS[w][rr][k] = (lgpS[w][rr][k] - mxS[16 * w + rr]) - ldS[16 * w + rr];
  }

  // sampling: halves of the wave; 32 (row,s4) units per half
  {
    int half = l >> 5, k = l & 31;
    for (int u = 0; u < 32; ++u) {
      int unit = 2 * u + half;
      int rr = unit >> 2, s4 = unit & 3;
      int node = 16 * w + rr;
      float lp = lgpS[w][rr][k];
      unsigned flat = (unsigned)(s4 * 32768 + b * 64 + node) * 32u + (unsigned)k;
      unsigned bits = tf_bits(flat);
      float fu = __uint_as_float((bits >> 9) | 0x3f800000u) - 1.0f;
      float uu = fmaxf(TINYF, fadd_s(fmul_s(fu, 1.0f - TINYF), TINYF));
      float g = -logf(-logf(uu));
      float v = lp + g;
      int bi = k;
#pragma unroll
      for (int d = 1; d < 32; d <<= 1) {        // max, first-index ties
        float ov = __shfl_xor(v, d, 32);
        int oi = __shfl_xor(bi, d, 32);
        if (ov > v || (ov == v && oi < bi)) { v = ov; bi = oi; }
      }
      if (k == 0) {
        conc[s4 * 32768 + b * 64 + node] = bi;
        pp[s4 * 32768 + b * 64 + node] = expf(lgpS[w][rr][bi]);
      }
    }
  }
}

// ---------------------------------------------------------------------------
// Per (s,b) sample: CC min-label fixpoint + graph_prob + labels + pooled
// adjacency + scatter-mean new_x.  One wave per block, 2048 blocks.
// ---------------------------------------------------------------------------
__global__ __launch_bounds__(64) void k_post(const int* __restrict__ conc,
                                             const float* __restrict__ pp,
                                             const float* __restrict__ maskf,
                                             const unsigned long long* __restrict__ nbr,
                                             const float* __restrict__ h,
                                             float* __restrict__ out_newx,
                                             float* __restrict__ out_newadj,
                                             float* __restrict__ out_gp,
                                             float* __restrict__ out_lab) {
  __shared__ int cs[64];
  __shared__ int labF[64];
  __shared__ unsigned char o[4096];

  int sb = blockIdx.x, b = sb & 511, lane = threadIdx.x;
  const float* hb = h + (size_t)b * 16384;

  int c0 = conc[sb * 64 + lane];
  cs[lane] = c0;
  bool mk = maskf[b * 64 + lane] != 0.0f;
  unsigned long long nb = nbr[b * 64 + lane];
  unsigned long long sm = 0ull;
  {
    unsigned long long t = nb;
    while (t) { int j = __ffsll(t) - 1; if (cs[j] == c0) sm |= (1ull << j); t &= t - 1; }
  }
  labF[lane] = lane + 1;                      // wave-lockstep Jacobi fixpoint
  for (int it = 0; it < 64; ++it) {
    int m = labF[lane];
    unsigned long long t = sm;
    while (t) { int j = __ffsll(t) - 1; m = min(m, labF[j]); t &= t - 1; }
    bool ch = m < labF[lane];
    if (ch) labF[lane] = m;
    if (!__any(ch)) break;
  }
  int lf = mk ? labF[lane] : 0;
  out_lab[(size_t)sb * 64 + lane] = (float)lf;
  float pv = mk ? pp[sb * 64 + lane] : 1.0f;
#pragma unroll
  for (int d = 1; d < 64; d <<= 1) pv *= __shfl_xor(pv, d, 64);
  if (lane == 0) out_gp[sb] = pv;
  labF[lane] = lf;                            // final masked labels (lockstep)
  unsigned long long cm = 0ull;
  for (int j = 0; j < 64; ++j)
    if (labF[j] == lane + 1) cm |= (1ull << j);
  // pooled adjacency (byte bitmap)
  {
    unsigned* op = (unsigned*)o;
#pragma unroll
    for (int u = 0; u < 16; ++u) op[u * 64 + lane] = 0u;
    if (lf > 0) {
      unsigned long long t = nb;
      while (t) {
        int j = __ffsll(t) - 1; t &= t - 1;
        int lj = labF[j];
        if (lj > 0) o[(lf - 1) * 64 + (lj - 1)] = 1;
      }
    }
    float* dA = out_newadj + (size_t)sb * 4096;
#pragma unroll
    for (int u = 0; u < 16; ++u) {
      int base = u * 256 + lane * 4;
      fx4 v;
      v.x = o[base + 0] ? 1.0f : 0.0f;
      v.y = o[base + 1] ? 1.0f : 0.0f;
      v.z = o[base + 2] ? 1.0f : 0.0f;
      v.w = o[base + 3] ? 1.0f : 0.0f;
      *(fx4*)&dA[base] = v;
    }
  }
  // scatter-mean new_x from global h (coalesced 1 KB lines, L2/L3-hot)
  float* dX = out_newx + (size_t)sb * 16384;
  for (int c = 0; c < 64; ++c) {
    unsigned long long m = __shfl(cm, c, 64);
    float4 acc4 = make_float4(0.f, 0.f, 0.f, 0.f);
    unsigned long long t = m;
    while (t) {
      int j = __ffsll(t) - 1; t &= t - 1;
      float4 v = *(const float4*)&hb[j * 256 + lane * 4];
      acc4.x += v.x; acc4.y += v.y; acc4.z += v.z; acc4.w += v.w;
    }
    int cnt = __popcll(m);
    float cf = (float)(cnt > 0 ? cnt : 1);
    fx4 r;
    r.x = acc4.x / cf; r.y = acc4.y / cf; r.z = acc4.z / cf; r.w = acc4.w / cf;
    *(fx4*)&dX[(size_t)c * 256 + lane * 4] = r;
  }
}

// ---------------------------------------------------------------------------
extern "C" void kernel_launch(void* const* d_in, const int* in_sizes, int n_in,
                              void* d_out, int out_size, void* d_ws, size_t ws_size,
                              hipStream_t stream) {
  (void)in_sizes; (void)n_in; (void)out_size; (void)ws_size;
  const float* x   = (const float*)d_in[0];
  const float* adj = (const float*)d_in[1];
  const void*  mp  = d_in[2];
  const float* W1  = (const float*)d_in[3];
  const float* b1  = (const float*)d_in[4];
  const float* W2  = (const float*)d_in[5];
  const float* b2  = (const float*)d_in[6];
  const float* cen = (const float*)d_in[7];

  char* ws = (char*)d_ws;
  unsigned short* Wg1  = (unsigned short*)(ws + 0);          // 196,608
  unsigned short* Wg2  = (unsigned short*)(ws + 196608);     // 393,216
  unsigned short* cen3 = (unsigned short*)(ws + 589824);     // 49,152
  float* ccbuf         = (float*)(ws + 638976);              // 128
  unsigned long long* nbr = (unsigned long long*)(ws + 655360);  // 262,144
  float* maskf         = (float*)(ws + 917504);              // 131,072
  int*   conc          = (int*)(ws + 1048576);               // 524,288
  float* pp            = (float*)(ws + 1572864);             // 524,288
  float* bufA          = (float*)(ws + 2097152);             // 33,554,432 (h1)
  float* bufB          = (float*)(ws + 37748736);            // 33,554,432 (h)

  float* out        = (float*)d_out;
  float* out_newx   = out;                 // 2048*64*256
  float* out_newadj = out + 33554432;      // 2048*64*64
  float* out_gp     = out + 41943040;      // 2048
  float* out_lab    = out + 41945088;      // 2048*64

  hipLaunchKernelGGL(k_setup, dim3(148), dim3(256), 0, stream, W1, W2, cen, Wg1, Wg2, cen3, ccbuf);
  hipLaunchKernelGGL(k_fused, dim3(512), dim3(256), 0, stream, x, adj, mp, b1, b2,
                     Wg1, Wg2, nbr, maskf, bufA, bufB);
  hipLaunchKernelGGL(k_cd,    dim3(512), dim3(256), 0, stream, bufB, cen3, ccbuf, conc, pp);
  hipLaunchKernelGGL(k_post,  dim3(2048), dim3(64), 0, stream, conc, pp, maskf, nbr, bufB,
                     out_newx, out_newadj, out_gp, out_lab);
}

// Round 12
// 149.717 us; speedup vs baseline: 1.0284x; 1.0284x over previous
//
#include <hip/hip_runtime.h>

#define B_    512

static constexpr float TINYF = 1.17549435e-38f;
typedef float fx4  __attribute__((ext_vector_type(4)));
typedef short bf16x8 __attribute__((ext_vector_type(8)));
typedef float f32x4 __attribute__((ext_vector_type(4)));
typedef unsigned short u16x4 __attribute__((ext_vector_type(4)));

// Contraction-pinned fp32 ops (RN, no fma fusion possible across these).
__device__ __forceinline__ float fmul_s(float a, float b) { float r; asm("v_mul_f32 %0, %1, %2" : "=v"(r) : "v"(a), "v"(b)); return r; }
__device__ __forceinline__ float fadd_s(float a, float b) { float r; asm("v_add_f32 %0, %1, %2" : "=v"(r) : "v"(a), "v"(b)); return r; }
__device__ __forceinline__ float fsub_s(float a, float b) { float r; asm("v_sub_f32 %0, %1, %2" : "=v"(r) : "v"(a), "v"(b)); return r; }

// ---------------------------------------------------------------------------
// Threefry-2x32, key = (0, 42), partitionable path.
// ---------------------------------------------------------------------------
__device__ __forceinline__ unsigned tf_bits(unsigned lo) {
  const unsigned ks0 = 0u, ks1 = 42u, ks2 = 0x1BD11BF0u;
  unsigned x0 = 0u + ks0;
  unsigned x1 = lo + ks1;
#define TFR(r) { x0 += x1; x1 = (x1 << r) | (x1 >> (32 - r)); x1 ^= x0; }
  TFR(13) TFR(15) TFR(26) TFR(6)
  x0 += ks1; x1 += ks2 + 1u;
  TFR(17) TFR(29) TFR(16) TFR(24)
  x0 += ks2; x1 += ks0 + 2u;
  TFR(13) TFR(15) TFR(26) TFR(6)
  x0 += ks0; x1 += ks1 + 3u;
  TFR(17) TFR(29) TFR(16) TFR(24)
  x0 += ks1; x1 += ks2 + 4u;
  TFR(13) TFR(15) TFR(26) TFR(6)
  x0 += ks2; x1 += ks0 + 5u;
#undef TFR
  return x0 ^ x1;
}

// Exact fp32 -> 3x bf16 split (truncation)
__device__ __forceinline__ void split3(float v, unsigned& b1, unsigned& b2, unsigned& b3) {
  unsigned u1 = __float_as_uint(v) & 0xFFFF0000u;
  float r1 = v - __uint_as_float(u1);
  unsigned u2 = __float_as_uint(r1) & 0xFFFF0000u;
  float r2 = r1 - __uint_as_float(u2);
  unsigned u3 = __float_as_uint(r2) & 0xFFFF0000u;
  b1 = u1 >> 16; b2 = u2 >> 16; b3 = u3 >> 16;
}

__device__ __forceinline__ unsigned short planeOf(float v, int s) {
  unsigned u1 = __float_as_uint(v) & 0xFFFF0000u;
  if (s == 0) return (unsigned short)(u1 >> 16);
  float r1 = v - __uint_as_float(u1);
  unsigned u2 = __float_as_uint(r1) & 0xFFFF0000u;
  if (s == 1) return (unsigned short)(u2 >> 16);
  float r2 = r1 - __uint_as_float(u2);
  return (unsigned short)((__float_as_uint(r2) & 0xFFFF0000u) >> 16);
}

// 6-product split accumulation (drops terms <= 2^-27 relative)
#define MF6(A0, A1, A2, Bv0, Bv1, Bv2, ACC)                                   \
  ACC = __builtin_amdgcn_mfma_f32_16x16x32_bf16(A0, Bv0, ACC, 0, 0, 0);       \
  ACC = __builtin_amdgcn_mfma_f32_16x16x32_bf16(A0, Bv1, ACC, 0, 0, 0);       \
  ACC = __builtin_amdgcn_mfma_f32_16x16x32_bf16(A1, Bv0, ACC, 0, 0, 0);       \
  ACC = __builtin_amdgcn_mfma_f32_16x16x32_bf16(A0, Bv2, ACC, 0, 0, 0);       \
  ACC = __builtin_amdgcn_mfma_f32_16x16x32_bf16(A1, Bv1, ACC, 0, 0, 0);       \
  ACC = __builtin_amdgcn_mfma_f32_16x16x32_bf16(A2, Bv0, ACC, 0, 0, 0);

// ---------------------------------------------------------------------------
// Setup: W1/W2 split planes, centroid norms, centroid split planes.
// ---------------------------------------------------------------------------
__global__ void k_setup(const float* __restrict__ W1, const float* __restrict__ W2,
                        const float* __restrict__ cen,
                        unsigned short* __restrict__ Wg1, unsigned short* __restrict__ Wg2,
                        unsigned short* __restrict__ cen3, float* __restrict__ ccbuf) {
  int bi = blockIdx.x, tid = threadIdx.x;
  if (bi < 144) {
    const float* W; unsigned short* Wg; int nk, s, ks, g;
    if (bi < 48) { W = W1; Wg = Wg1; nk = 4; s = bi >> 4; ks = (bi >> 2) & 3; g = bi & 3; }
    else { int t = bi - 48; W = W2; Wg = Wg2; nk = 8; s = t >> 5; ks = (t >> 2) & 7; g = t & 3; }
    int n = tid;
    bf16x8 hv;
#pragma unroll
    for (int jj = 0; jj < 8; ++jj) {
      float v = W[(size_t)(ks * 32 + g * 8 + jj) * 256 + n];
      hv[jj] = (short)planeOf(v, s);
    }
    *(bf16x8*)&Wg[((((size_t)s * nk + ks) * 4 + g) * 256 + n) * 8] = hv;
  } else if (bi == 144) {
    int k = tid >> 3, l8 = tid & 7;
    float s = 0.0f;
    for (int m = 0; m < 32; ++m) { float v = cen[k * 256 + l8 + 8 * m]; s += v * v; }
#pragma unroll
    for (int d = 1; d < 8; d <<= 1) s += __shfl_xor(s, d, 64);
    if (l8 == 0) ccbuf[k] = s;
  } else {
    int s = bi - 145;
    for (int u = 0; u < 4; ++u) {
      int idx = tid + 256 * u;
      int ks = idx >> 7, c = (idx >> 6) & 1, rem = idx & 63;
      int l15v = rem >> 2, lgv = rem & 3;
      bf16x8 hv;
#pragma unroll
      for (int jj = 0; jj < 8; ++jj)
        hv[jj] = (short)planeOf(cen[(size_t)(16 * c + l15v) * 256 + 32 * ks + 8 * lgv + jj], s);
      *(bf16x8*)&cen3[(size_t)s * 8192 + (size_t)idx * 8] = hv;
    }
  }
}

// ---------------------------------------------------------------------------
// Layer core (global->global): out = relu(maskS * (Ahat @ (A @ W) + biaS)).
// ---------------------------------------------------------------------------
__device__ __forceinline__ void layer_core(const float* __restrict__ A,
                                           const unsigned short* __restrict__ Wg,
                                           const unsigned short* AhP,
                                           const float* biaS, const float* maskS,
                                           float* __restrict__ out, int nk,
                                           char* U, int b, int tid) {
  unsigned short (*Ap)[3][2112] = (unsigned short(*)[3][2112])U;  // [2][3][2112]
  unsigned short (*Tbuf)[72]    = (unsigned short(*)[72])U;       // [256][72]
  int w = tid >> 6, l = tid & 63;
  int l15 = l & 15, lg = l >> 4;
  int K = nk * 32;
  int srow = tid >> 2, sg = tid & 3;
  const float* sp = A + (size_t)srow * K + sg * 8;

  // stage K-step 0 into buffer 0
  {
    float4 v0 = *(const float4*)(sp);
    float4 v1 = *(const float4*)(sp + 4);
    float vv[8] = {v0.x, v0.y, v0.z, v0.w, v1.x, v1.y, v1.z, v1.w};
    bf16x8 p1, p2, p3;
#pragma unroll
    for (int jj = 0; jj < 8; ++jj) {
      unsigned h1, h2, h3; split3(vv[jj], h1, h2, h3);
      p1[jj] = (short)h1; p2[jj] = (short)h2; p3[jj] = (short)h3;
    }
    int off = sg * 528 + srow * 8;
    *(bf16x8*)&Ap[0][0][off] = p1;
    *(bf16x8*)&Ap[0][1][off] = p2;
    *(bf16x8*)&Ap[0][2][off] = p3;
  }
  __syncthreads();

  f32x4 acc1[4][4];
#pragma unroll
  for (int q = 0; q < 4; ++q)
#pragma unroll
    for (int c = 0; c < 4; ++c) acc1[q][c] = (f32x4){0.f, 0.f, 0.f, 0.f};

  const size_t wss = (size_t)nk * 8192;

  for (int ks = 0; ks < nk; ++ks) {
    int cur = ks & 1;
    float4 v0, v1;
    bool pf = (ks + 1 < nk);
    if (pf) {
      v0 = *(const float4*)(sp + (ks + 1) * 32);
      v1 = *(const float4*)(sp + (ks + 1) * 32 + 4);
    }
    bf16x8 af[4][3];
#pragma unroll
    for (int q = 0; q < 4; ++q) {
      int off = lg * 528 + (16 * q + l15) * 8;
#pragma unroll
      for (int s = 0; s < 3; ++s) af[q][s] = *(const bf16x8*)&Ap[cur][s][off];
    }
#pragma unroll
    for (int c = 0; c < 4; ++c) {
      size_t wbase = (((size_t)ks * 4 + lg) * 256 + (64 * w + 16 * c + l15)) * 8;
      bf16x8 b0 = *(const bf16x8*)&Wg[wbase];
      bf16x8 b1 = *(const bf16x8*)&Wg[wbase + wss];
      bf16x8 b2 = *(const bf16x8*)&Wg[wbase + 2 * wss];
#pragma unroll
      for (int q = 0; q < 4; ++q) {
        MF6(af[q][0], af[q][1], af[q][2], b0, b1, b2, acc1[q][c]);
      }
    }
    if (pf) {
      float vv[8] = {v0.x, v0.y, v0.z, v0.w, v1.x, v1.y, v1.z, v1.w};
      bf16x8 p1, p2, p3;
#pragma unroll
      for (int jj = 0; jj < 8; ++jj) {
        unsigned h1, h2, h3; split3(vv[jj], h1, h2, h3);
        p1[jj] = (short)h1; p2[jj] = (short)h2; p3[jj] = (short)h3;
      }
      int off = sg * 528 + srow * 8;
      *(bf16x8*)&Ap[cur ^ 1][0][off] = p1;
      *(bf16x8*)&Ap[cur ^ 1][1][off] = p2;
      *(bf16x8*)&Ap[cur ^ 1][2][off] = p3;
    }
    __syncthreads();
  }

  // GEMM#2 phased over T split-planes sB; product budget nA = 3 - sB.
  f32x4 acc2[4][4];
#pragma unroll
  for (int q = 0; q < 4; ++q)
#pragma unroll
    for (int c = 0; c < 4; ++c) acc2[q][c] = (f32x4){0.f, 0.f, 0.f, 0.f};

#pragma unroll
  for (int sB = 0; sB < 3; ++sB) {
    const int nA = 3 - sB;
    __syncthreads();
#pragma unroll
    for (int q = 0; q < 4; ++q)
#pragma unroll
      for (int c = 0; c < 4; ++c) {
        u16x4 pv;
#pragma unroll
        for (int r = 0; r < 4; ++r) pv[r] = planeOf(acc1[q][c][r], sB);
        *(u16x4*)&Tbuf[64 * w + 16 * c + l15][16 * q + 4 * lg] = pv;
      }
    __syncthreads();
#pragma unroll
    for (int mt = 0; mt < 2; ++mt) {
      bf16x8 bf[4];
#pragma unroll
      for (int c = 0; c < 4; ++c)
        bf[c] = *(const bf16x8*)&Tbuf[64 * w + 16 * c + l15][32 * mt + 8 * lg];
#pragma unroll
      for (int q2 = 0; q2 < 4; ++q2) {
        bf16x8 afr[3];
#pragma unroll
        for (int sA = 0; sA < 3; ++sA)
          if (sA < nA)
            afr[sA] = *(const bf16x8*)&AhP[((((size_t)(sA * 2 + mt) * 4 + q2) * 4 + lg) * 16 + l15) * 8];
#pragma unroll
        for (int c = 0; c < 4; ++c)
#pragma unroll
          for (int sA = 0; sA < 3; ++sA)
            if (sA < nA)
              acc2[q2][c] = __builtin_amdgcn_mfma_f32_16x16x32_bf16(afr[sA], bf[c], acc2[q2][c], 0, 0, 0);
      }
    }
  }

  // epilogue: (acc + bias) * mask, relu -> global
#pragma unroll
  for (int q2 = 0; q2 < 4; ++q2) {
#pragma unroll
    for (int c = 0; c < 4; ++c) {
      int n = 64 * w + 16 * c + l15;
      float bv = biaS[n];
#pragma unroll
      for (int r = 0; r < 4; ++r) {
        int row = 16 * q2 + 4 * lg + r;
        float val = (acc2[q2][c][r] + bv) * maskS[row];
        out[((size_t)b * 64 + row) * 256 + n] = fmaxf(val, 0.0f);
      }
    }
  }
}

// ---------------------------------------------------------------------------
// Fused prep + layer1 + layer2.  63 KB LDS -> 2 blocks/CU.
// ---------------------------------------------------------------------------
__global__ __launch_bounds__(256, 2) void k_fused(
    const float* __restrict__ x, const float* __restrict__ adj,
    const void* __restrict__ mp,
    const float* __restrict__ b1v, const float* __restrict__ b2v,
    const unsigned short* __restrict__ Wg1, const unsigned short* __restrict__ Wg2,
    unsigned long long* __restrict__ nbr, float* __restrict__ maskf,
    float* __restrict__ bufA, float* __restrict__ bufB) {
  __shared__ unsigned short AhP[12288];      // 24.6 KB
  __shared__ float biaS[256];
  __shared__ float maskS[64];
  __shared__ int s_ni, s_nf;
  __shared__ __align__(16) char U[36864];    // union: prep 33.3K / layers 36.9K

  int b = blockIdx.x, tid = threadIdx.x;

  // ===== phase 0: prep =====
  {
    float* adjS = (float*)U;
    float (*AhS)[65] = (float(*)[65])(U + 16384);
    float* dis = (float*)(U + 33024);
    if (tid == 0) { s_ni = 0; s_nf = 0; }
    const float* ab = adj + (size_t)b * 4096;
    for (int i = tid; i < 4096; i += 256) adjS[i] = ab[i];
    {
      const unsigned* wp = (const unsigned*)mp;
      int ni = 0, nf = 0;
      for (int i = tid; i < 2048; i += 256) {
        unsigned v = wp[i];
        if (v > 1u) ni = 1;
        if (v != 0u && v != 0x3f800000u) nf = 1;
      }
      if (ni) atomicOr(&s_ni, 1);
      if (nf) atomicOr(&s_nf, 1);
    }
    biaS[tid] = b1v[tid];
    __syncthreads();
    if (tid < 64) {
      float s = 0.0f;
      unsigned long long m = 0ull;
      for (int j = 0; j < 64; ++j) {
        float v = adjS[j * 64 + tid];          // symmetric
        s += (j == tid) ? (v + 1.0f) : v;
        if (v != 0.0f) m |= (1ull << j);
      }
      dis[tid] = 1.0f / sqrtf(fmaxf(s, 1.0f));
      nbr[b * 64 + tid] = m;
      int fl = s_ni ? (s_nf ? 2 : 1) : 0;
      int i = b * 64 + tid;
      float r;
      if (fl == 0)      r = ((const int*)mp)[i] ? 1.0f : 0.0f;
      else if (fl == 1) r = (((const float*)mp)[i] != 0.0f) ? 1.0f : 0.0f;
      else              r = ((const unsigned char*)mp)[i] ? 1.0f : 0.0f;
      maskS[tid] = r;
      maskf[i] = r;
    }
    __syncthreads();
    for (int i = tid; i < 4096; i += 256) {
      int r = i >> 6, c = i & 63;
      float a = adjS[i] + ((r == c) ? 1.0f : 0.0f);
      AhS[r][c] = (dis[r] * a) * dis[c];
    }
    __syncthreads();
    for (int ch = tid; ch < 1536; ch += 256) {
      int l15v = ch & 15, lgv = (ch >> 4) & 3, q2 = (ch >> 6) & 3, mt = (ch >> 8) & 1, s = ch >> 9;
      bf16x8 hv;
#pragma unroll
      for (int jj = 0; jj < 8; ++jj)
        hv[jj] = (short)planeOf(AhS[16 * q2 + l15v][32 * mt + 8 * lgv + jj], s);
      *(bf16x8*)&AhP[(size_t)ch * 8] = hv;
    }
    __syncthreads();
  }

  // ===== phase 1: layer1 (x -> bufA) =====
  layer_core(x + (size_t)b * 64 * 128, Wg1, AhP, biaS, maskS, bufA, 4, U, b, tid);
  __syncthreads();
  biaS[tid] = b2v[tid];

  // ===== phase 2: layer2 (bufA -> bufB) =====
  layer_core(bufA + (size_t)b * 64 * 256, Wg2, AhP, biaS, maskS, bufB, 8, U, b, tid);
}

// ---------------------------------------------------------------------------
// cdist + softmin + Gumbel-max sampling + per-wave CC/newadj/newx/gp/lab.
// h read directly from global (L2-hot, written by k_fused).  49.9 KB LDS ->
// 3 blocks/CU.  Regular (L2-allocating) output stores.
// ---------------------------------------------------------------------------
__global__ __launch_bounds__(256, 3) void k_cdsp(const float* __restrict__ h,
                                                 const unsigned short* __restrict__ cen3,
                                                 const float* __restrict__ ccbuf,
                                                 const float* __restrict__ maskf,
                                                 const unsigned long long* __restrict__ nbr,
                                                 float* __restrict__ out_newx,
                                                 float* __restrict__ out_newadj,
                                                 float* __restrict__ out_gp,
                                                 float* __restrict__ out_lab) {
  __shared__ float Dred[4][64][36];    // 36.9 KB (reused as newadj bitmap in phase 4)
  __shared__ float hhp[64][4];
  __shared__ float lgp[64][33];
  __shared__ float mxs[64], lgden[64];
  __shared__ int concS[4][64];
  __shared__ float ppS[4][64];
  __shared__ int labFS[4][64];

  int b = blockIdx.x, tid = threadIdx.x;
  int w = tid >> 6, l = tid & 63, l15 = l & 15, lg = l >> 4;
  const float* hb = h + (size_t)b * 16384;

  // hh partials: thread t -> row t&63, f-quarter t>>6 (global reads, L2-hot)
  {
    int row = tid & 63, qt = tid >> 6;
    float s = 0.0f;
    for (int u = 0; u < 16; ++u) {
      float4 v = *(const float4*)&hb[row * 256 + qt * 64 + u * 4];
      float t = fadd_s(fadd_s(fadd_s(fmul_s(v.x, v.x), fmul_s(v.y, v.y)), fmul_s(v.z, v.z)), fmul_s(v.w, v.w));
      s = fadd_s(s, t);
    }
    hhp[row][qt] = s;
  }

  f32x4 acc[4][2];
#pragma unroll
  for (int qt = 0; qt < 4; ++qt)
#pragma unroll
    for (int c = 0; c < 2; ++c) acc[qt][c] = (f32x4){0.f, 0.f, 0.f, 0.f};

#pragma unroll
  for (int ks2 = 0; ks2 < 2; ++ks2) {
    int ks = 2 * w + ks2;
#pragma unroll
    for (int qt = 0; qt < 4; ++qt) {
      int row = 16 * qt + l15;
      float4 v0 = *(const float4*)&hb[row * 256 + 32 * ks + 8 * lg];
      float4 v1 = *(const float4*)&hb[row * 256 + 32 * ks + 8 * lg + 4];
      float vv[8] = {v0.x, v0.y, v0.z, v0.w, v1.x, v1.y, v1.z, v1.w};
      bf16x8 a0, a1, a2;
#pragma unroll
      for (int jj = 0; jj < 8; ++jj) {
        unsigned h1, h2, h3; split3(vv[jj], h1, h2, h3);
        a0[jj] = (short)h1; a1[jj] = (short)h2; a2[jj] = (short)h3;
      }
#pragma unroll
      for (int c = 0; c < 2; ++c) {
        const unsigned short* cb = cen3 + ((size_t)(ks * 2 + c) * 64 + l15 * 4 + lg) * 8;
        bf16x8 b0 = *(const bf16x8*)cb;
        bf16x8 b1 = *(const bf16x8*)(cb + 8192);
        bf16x8 b2 = *(const bf16x8*)(cb + 16384);
        MF6(a0, a1, a2, b0, b1, b2, acc[qt][c]);
      }
    }
  }

#pragma unroll
  for (int qt = 0; qt < 4; ++qt)
#pragma unroll
    for (int c = 0; c < 2; ++c)
#pragma unroll
      for (int r = 0; r < 4; ++r)
        Dred[w][16 * qt + 4 * lg + r][16 * c + l15] = acc[qt][c][r];
  __syncthreads();

  {
    int n = tid >> 2, kq = tid & 3;
    float hh = (hhp[n][0] + hhp[n][1]) + (hhp[n][2] + hhp[n][3]);
#pragma unroll
    for (int j = 0; j < 8; ++j) {
      int k = kq * 8 + j;
      float dot = (Dred[0][n][k] + Dred[1][n][k]) + (Dred[2][n][k] + Dred[3][n][k]);
      float d2 = fsub_s(fadd_s(hh, ccbuf[k]), fmul_s(2.0f, dot));
      lgp[n][k] = -10.0f * sqrtf(fmaxf(d2, 1e-12f));
    }
  }
  __syncthreads();

  if (tid < 64) {
    float mx = -1e30f;
    for (int k = 0; k < 32; ++k) mx = fmaxf(mx, lgp[tid][k]);
    float den = 0.0f;
    for (int k = 0; k < 32; ++k) den += expf(lgp[tid][k] - mx);
    mxs[tid] = mx; lgden[tid] = logf(den);
  }
  __syncthreads();
  for (int p = tid; p < 2048; p += 256) {
    int n = p >> 5, k = p & 31;
    lgp[n][k] = (lgp[n][k] - mxs[n]) - lgden[n];
  }
  __syncthreads();

  {
    int hw = tid >> 5, k = tid & 31;
    for (int pass = 0; pass < 8; ++pass) {
      int n = hw * 8 + pass;
      float lp = lgp[n][k];
#pragma unroll
      for (int s4 = 0; s4 < 4; ++s4) {
        unsigned flat = (unsigned)(s4 * 32768 + b * 64 + n) * 32u + (unsigned)k;
        unsigned bits = tf_bits(flat);
        float fu = __uint_as_float((bits >> 9) | 0x3f800000u) - 1.0f;
        float u = fmaxf(TINYF, fadd_s(fmul_s(fu, 1.0f - TINYF), TINYF));
        float g = -logf(-logf(u));
        float v = lp + g;
        int bi = k;
#pragma unroll
        for (int d = 1; d < 32; d <<= 1) {      // max, first-index ties
          float ov = __shfl_xor(v, d, 32);
          int oi = __shfl_xor(bi, d, 32);
          if (ov > v || (ov == v && oi < bi)) { v = ov; bi = oi; }
        }
        if (k == 0) {
          concS[s4][n] = bi;
          ppS[s4][n] = expf(lgp[n][bi]);
        }
      }
    }
  }
  __syncthreads();

  // ===== phase 4: per-wave (sample = wave) CC + outputs =====
  {
    unsigned char (*o)[4096] = (unsigned char(*)[4096])Dred;
    int s = w, lane = l;
    int sbo = s * 512 + b;
    int c0 = concS[s][lane];
    bool mk = maskf[b * 64 + lane] != 0.0f;
    unsigned long long nb = nbr[b * 64 + lane];
    unsigned long long sm = 0ull;
    {
      unsigned long long t = nb;
      while (t) { int j = __ffsll(t) - 1; if (concS[s][j] == c0) sm |= (1ull << j); t &= t - 1; }
    }
    labFS[s][lane] = lane + 1;                  // wave-lockstep Jacobi fixpoint
    for (int it = 0; it < 64; ++it) {
      int m = labFS[s][lane];
      unsigned long long t = sm;
      while (t) { int j = __ffsll(t) - 1; m = min(m, labFS[s][j]); t &= t - 1; }
      bool ch = m < labFS[s][lane];
      if (ch) labFS[s][lane] = m;
      if (!__any(ch)) break;
    }
    int lf = mk ? labFS[s][lane] : 0;
    out_lab[(size_t)sbo * 64 + lane] = (float)lf;
    float pv = mk ? ppS[s][lane] : 1.0f;
#pragma unroll
    for (int d = 1; d < 64; d <<= 1) pv *= __shfl_xor(pv, d, 64);
    if (lane == 0) out_gp[sbo] = pv;
    labFS[s][lane] = lf;                        // final masked labels (lockstep)
    unsigned long long cm = 0ull;
    for (int j = 0; j < 64; ++j)
      if (labFS[s][j] == lane + 1) cm |= (1ull << j);
    // pooled adjacency (byte bitmap per sample)
    {
      unsigned* op = (unsigned*)o[s];
#pragma unroll
      for (int u = 0; u < 16; ++u) op[u * 64 + lane] = 0u;
      if (lf > 0) {
        unsigned long long t = nb;
        while (t) {
          int j = __ffsll(t) - 1; t &= t - 1;
          int lj = labFS[s][j];
          if (lj > 0) o[s][(lf - 1) * 64 + (lj - 1)] = 1;
        }
      }
      float* dA = out_newadj + (size_t)sbo * 4096;
#pragma unroll
      for (int u = 0; u < 16; ++u) {
        int base = u * 256 + lane * 4;
        fx4 v;
        v.x = o[s][base + 0] ? 1.0f : 0.0f;
        v.y = o[s][base + 1] ? 1.0f : 0.0f;
        v.z = o[s][base + 2] ? 1.0f : 0.0f;
        v.w = o[s][base + 3] ? 1.0f : 0.0f;
        *(fx4*)&dA[base] = v;
      }
    }
    // scatter-mean new_x from global h (coalesced 1 KB lines, L2-hot)
    float* dX = out_newx + (size_t)sbo * 16384;
    for (int c = 0; c < 64; ++c) {
      unsigned long long m = __shfl(cm, c, 64);
      float4 acc4 = make_float4(0.f, 0.f, 0.f, 0.f);
      unsigned long long t = m;
      while (t) {
        int j = __ffsll(t) - 1; t &= t - 1;
        float4 v = *(const float4*)&hb[j * 256 + lane * 4];
        acc4.x += v.x; acc4.y += v.y; acc4.z += v.z; acc4.w += v.w;
      }
      int cnt = __popcll(m);
      float cf = (float)(cnt > 0 ? cnt : 1);
      fx4 r;
      r.x = acc4.x / cf; r.y = acc4.y / cf; r.z = acc4.z / cf; r.w = acc4.w / cf;
      *(fx4*)&dX[(size_t)c * 256 + lane * 4] = r;
    }
  }
}

// ---------------------------------------------------------------------------
extern "C" void kernel_launch(void* const* d_in, const int* in_sizes, int n_in,
                              void* d_out, int out_size, void* d_ws, size_t ws_size,
                              hipStream_t stream) {
  (void)in_sizes; (void)n_in; (void)out_size; (void)ws_size;
  const float* x   = (const float*)d_in[0];
  const float* adj = (const float*)d_in[1];
  const void*  mp  = d_in[2];
  const float* W1  = (const float*)d_in[3];
  const float* b1  = (const float*)d_in[4];
  const float* W2  = (const float*)d_in[5];
  const float* b2  = (const float*)d_in[6];
  const float* cen = (const float*)d_in[7];

  char* ws = (char*)d_ws;
  unsigned short* Wg1  = (unsigned short*)(ws + 0);          // 196,608
  unsigned short* Wg2  = (unsigned short*)(ws + 196608);     // 393,216
  unsigned short* cen3 = (unsigned short*)(ws + 589824);     // 49,152
  float* ccbuf         = (float*)(ws + 638976);              // 128
  unsigned long long* nbr = (unsigned long long*)(ws + 655360);  // 262,144
  float* maskf         = (float*)(ws + 917504);              // 131,072
  float* bufA          = (float*)(ws + 2097152);             // 33,554,432 (h1)
  float* bufB          = (float*)(ws + 37748736);            // 33,554,432 (h)

  float* out        = (float*)d_out;
  float* out_newx   = out;                 // 2048*64*256
  float* out_newadj = out + 33554432;      // 2048*64*64
  float* out_gp     = out + 41943040;      // 2048
  float* out_lab    = out + 41945088;      // 2048*64

  hipLaunchKernelGGL(k_setup, dim3(148), dim3(256), 0, stream, W1, W2, cen, Wg1, Wg2, cen3, ccbuf);
  hipLaunchKernelGGL(k_fused, dim3(512), dim3(256), 0, stream, x, adj, mp, b1, b2,
                     Wg1, Wg2, nbr, maskf, bufA, bufB);
  hipLaunchKernelGGL(k_cdsp,  dim3(512), dim3(256), 0, stream, bufB, cen3, ccbuf, maskf, nbr,
                     out_newx, out_newadj, out_gp, out_lab);
}

// Round 13
// 148.851 us; speedup vs baseline: 1.0343x; 1.0058x over previous
//
#include <hip/hip_runtime.h>

#define B_    512

static constexpr float TINYF = 1.17549435e-38f;
typedef float fx4  __attribute__((ext_vector_type(4)));
typedef short bf16x8 __attribute__((ext_vector_type(8)));
typedef float f32x4 __attribute__((ext_vector_type(4)));
typedef unsigned short u16x4 __attribute__((ext_vector_type(4)));

// Contraction-pinned fp32 ops (RN, no fma fusion possible across these).
__device__ __forceinline__ float fmul_s(float a, float b) { float r; asm("v_mul_f32 %0, %1, %2" : "=v"(r) : "v"(a), "v"(b)); return r; }
__device__ __forceinline__ float fadd_s(float a, float b) { float r; asm("v_add_f32 %0, %1, %2" : "=v"(r) : "v"(a), "v"(b)); return r; }
__device__ __forceinline__ float fsub_s(float a, float b) { float r; asm("v_sub_f32 %0, %1, %2" : "=v"(r) : "v"(a), "v"(b)); return r; }

// ---------------------------------------------------------------------------
// Threefry-2x32, key = (0, 42), partitionable path.
// ---------------------------------------------------------------------------
__device__ __forceinline__ unsigned tf_bits(unsigned lo) {
  const unsigned ks0 = 0u, ks1 = 42u, ks2 = 0x1BD11BF0u;
  unsigned x0 = 0u + ks0;
  unsigned x1 = lo + ks1;
#define TFR(r) { x0 += x1; x1 = (x1 << r) | (x1 >> (32 - r)); x1 ^= x0; }
  TFR(13) TFR(15) TFR(26) TFR(6)
  x0 += ks1; x1 += ks2 + 1u;
  TFR(17) TFR(29) TFR(16) TFR(24)
  x0 += ks2; x1 += ks0 + 2u;
  TFR(13) TFR(15) TFR(26) TFR(6)
  x0 += ks0; x1 += ks1 + 3u;
  TFR(17) TFR(29) TFR(16) TFR(24)
  x0 += ks1; x1 += ks2 + 4u;
  TFR(13) TFR(15) TFR(26) TFR(6)
  x0 += ks2; x1 += ks0 + 5u;
#undef TFR
  return x0 ^ x1;
}

// Exact fp32 -> 3x bf16 split (truncation)
__device__ __forceinline__ void split3(float v, unsigned& b1, unsigned& b2, unsigned& b3) {
  unsigned u1 = __float_as_uint(v) & 0xFFFF0000u;
  float r1 = v - __uint_as_float(u1);
  unsigned u2 = __float_as_uint(r1) & 0xFFFF0000u;
  float r2 = r1 - __uint_as_float(u2);
  unsigned u3 = __float_as_uint(r2) & 0xFFFF0000u;
  b1 = u1 >> 16; b2 = u2 >> 16; b3 = u3 >> 16;
}

__device__ __forceinline__ unsigned short planeOf(float v, int s) {
  unsigned u1 = __float_as_uint(v) & 0xFFFF0000u;
  if (s == 0) return (unsigned short)(u1 >> 16);
  float r1 = v - __uint_as_float(u1);
  unsigned u2 = __float_as_uint(r1) & 0xFFFF0000u;
  if (s == 1) return (unsigned short)(u2 >> 16);
  float r2 = r1 - __uint_as_float(u2);
  return (unsigned short)((__float_as_uint(r2) & 0xFFFF0000u) >> 16);
}

// 6-product split accumulation (drops terms <= 2^-27 relative)
#define MF6(A0, A1, A2, Bv0, Bv1, Bv2, ACC)                                   \
  ACC = __builtin_amdgcn_mfma_f32_16x16x32_bf16(A0, Bv0, ACC, 0, 0, 0);       \
  ACC = __builtin_amdgcn_mfma_f32_16x16x32_bf16(A0, Bv1, ACC, 0, 0, 0);       \
  ACC = __builtin_amdgcn_mfma_f32_16x16x32_bf16(A1, Bv0, ACC, 0, 0, 0);       \
  ACC = __builtin_amdgcn_mfma_f32_16x16x32_bf16(A0, Bv2, ACC, 0, 0, 0);       \
  ACC = __builtin_amdgcn_mfma_f32_16x16x32_bf16(A1, Bv1, ACC, 0, 0, 0);       \
  ACC = __builtin_amdgcn_mfma_f32_16x16x32_bf16(A2, Bv0, ACC, 0, 0, 0);

// ---------------------------------------------------------------------------
// Setup: W1/W2 split planes, centroid norms, centroid split planes.
// ---------------------------------------------------------------------------
__global__ void k_setup(const float* __restrict__ W1, const float* __restrict__ W2,
                        const float* __restrict__ cen,
                        unsigned short* __restrict__ Wg1, unsigned short* __restrict__ Wg2,
                        unsigned short* __restrict__ cen3, float* __restrict__ ccbuf) {
  int bi = blockIdx.x, tid = threadIdx.x;
  if (bi < 144) {
    const float* W; unsigned short* Wg; int nk, s, ks, g;
    if (bi < 48) { W = W1; Wg = Wg1; nk = 4; s = bi >> 4; ks = (bi >> 2) & 3; g = bi & 3; }
    else { int t = bi - 48; W = W2; Wg = Wg2; nk = 8; s = t >> 5; ks = (t >> 2) & 7; g = t & 3; }
    int n = tid;
    bf16x8 hv;
#pragma unroll
    for (int jj = 0; jj < 8; ++jj) {
      float v = W[(size_t)(ks * 32 + g * 8 + jj) * 256 + n];
      hv[jj] = (short)planeOf(v, s);
    }
    *(bf16x8*)&Wg[((((size_t)s * nk + ks) * 4 + g) * 256 + n) * 8] = hv;
  } else if (bi == 144) {
    int k = tid >> 3, l8 = tid & 7;
    float s = 0.0f;
    for (int m = 0; m < 32; ++m) { float v = cen[k * 256 + l8 + 8 * m]; s += v * v; }
#pragma unroll
    for (int d = 1; d < 8; d <<= 1) s += __shfl_xor(s, d, 64);
    if (l8 == 0) ccbuf[k] = s;
  } else {
    int s = bi - 145;
    for (int u = 0; u < 4; ++u) {
      int idx = tid + 256 * u;
      int ks = idx >> 7, c = (idx >> 6) & 1, rem = idx & 63;
      int l15v = rem >> 2, lgv = rem & 3;
      bf16x8 hv;
#pragma unroll
      for (int jj = 0; jj < 8; ++jj)
        hv[jj] = (short)planeOf(cen[(size_t)(16 * c + l15v) * 256 + 32 * ks + 8 * lgv + jj], s);
      *(bf16x8*)&cen3[(size_t)s * 8192 + (size_t)idx * 8] = hv;
    }
  }
}

// ---------------------------------------------------------------------------
// Layer core (global->global): out = relu(maskS * (Ahat @ (A @ W) + biaS)).
// GEMM#2's Tbuf is wave-local (wave w writes AND reads only cols 64w..64w+63),
// so the sB-phase barriers are unnecessary: sB=0 is protected by the ks-loop's
// final barrier; sB>=1 reuse is same-wave ordered (lgkmcnt).  No fp op change.
// ---------------------------------------------------------------------------
__device__ __forceinline__ void layer_core(const float* __restrict__ A,
                                           const unsigned short* __restrict__ Wg,
                                           const unsigned short* AhP,
                                           const float* biaS, const float* maskS,
                                           float* __restrict__ out, int nk,
                                           char* U, int b, int tid) {
  unsigned short (*Ap)[3][2112] = (unsigned short(*)[3][2112])U;  // [2][3][2112]
  unsigned short (*Tbuf)[72]    = (unsigned short(*)[72])U;       // [256][72]
  int w = tid >> 6, l = tid & 63;
  int l15 = l & 15, lg = l >> 4;
  int K = nk * 32;
  int srow = tid >> 2, sg = tid & 3;
  const float* sp = A + (size_t)srow * K + sg * 8;

  // stage K-step 0 into buffer 0
  {
    float4 v0 = *(const float4*)(sp);
    float4 v1 = *(const float4*)(sp + 4);
    float vv[8] = {v0.x, v0.y, v0.z, v0.w, v1.x, v1.y, v1.z, v1.w};
    bf16x8 p1, p2, p3;
#pragma unroll
    for (int jj = 0; jj < 8; ++jj) {
      unsigned h1, h2, h3; split3(vv[jj], h1, h2, h3);
      p1[jj] = (short)h1; p2[jj] = (short)h2; p3[jj] = (short)h3;
    }
    int off = sg * 528 + srow * 8;
    *(bf16x8*)&Ap[0][0][off] = p1;
    *(bf16x8*)&Ap[0][1][off] = p2;
    *(bf16x8*)&Ap[0][2][off] = p3;
  }
  __syncthreads();

  f32x4 acc1[4][4];
#pragma unroll
  for (int q = 0; q < 4; ++q)
#pragma unroll
    for (int c = 0; c < 4; ++c) acc1[q][c] = (f32x4){0.f, 0.f, 0.f, 0.f};

  const size_t wss = (size_t)nk * 8192;

  for (int ks = 0; ks < nk; ++ks) {
    int cur = ks & 1;
    float4 v0, v1;
    bool pf = (ks + 1 < nk);
    if (pf) {
      v0 = *(const float4*)(sp + (ks + 1) * 32);
      v1 = *(const float4*)(sp + (ks + 1) * 32 + 4);
    }
    bf16x8 af[4][3];
#pragma unroll
    for (int q = 0; q < 4; ++q) {
      int off = lg * 528 + (16 * q + l15) * 8;
#pragma unroll
      for (int s = 0; s < 3; ++s) af[q][s] = *(const bf16x8*)&Ap[cur][s][off];
    }
#pragma unroll
    for (int c = 0; c < 4; ++c) {
      size_t wbase = (((size_t)ks * 4 + lg) * 256 + (64 * w + 16 * c + l15)) * 8;
      bf16x8 b0 = *(const bf16x8*)&Wg[wbase];
      bf16x8 b1 = *(const bf16x8*)&Wg[wbase + wss];
      bf16x8 b2 = *(const bf16x8*)&Wg[wbase + 2 * wss];
#pragma unroll
      for (int q = 0; q < 4; ++q) {
        MF6(af[q][0], af[q][1], af[q][2], b0, b1, b2, acc1[q][c]);
      }
    }
    if (pf) {
      float vv[8] = {v0.x, v0.y, v0.z, v0.w, v1.x, v1.y, v1.z, v1.w};
      bf16x8 p1, p2, p3;
#pragma unroll
      for (int jj = 0; jj < 8; ++jj) {
        unsigned h1, h2, h3; split3(vv[jj], h1, h2, h3);
        p1[jj] = (short)h1; p2[jj] = (short)h2; p3[jj] = (short)h3;
      }
      int off = sg * 528 + srow * 8;
      *(bf16x8*)&Ap[cur ^ 1][0][off] = p1;
      *(bf16x8*)&Ap[cur ^ 1][1][off] = p2;
      *(bf16x8*)&Ap[cur ^ 1][2][off] = p3;
    }
    __syncthreads();
  }

  // GEMM#2 phased over T split-planes sB; product budget nA = 3 - sB.
  // Tbuf accesses are wave-local -> no barriers in this loop.
  f32x4 acc2[4][4];
#pragma unroll
  for (int q = 0; q < 4; ++q)
#pragma unroll
    for (int c = 0; c < 4; ++c) acc2[q][c] = (f32x4){0.f, 0.f, 0.f, 0.f};

#pragma unroll
  for (int sB = 0; sB < 3; ++sB) {
    const int nA = 3 - sB;
#pragma unroll
    for (int q = 0; q < 4; ++q)
#pragma unroll
      for (int c = 0; c < 4; ++c) {
        u16x4 pv;
#pragma unroll
        for (int r = 0; r < 4; ++r) pv[r] = planeOf(acc1[q][c][r], sB);
        *(u16x4*)&Tbuf[64 * w + 16 * c + l15][16 * q + 4 * lg] = pv;
      }
#pragma unroll
    for (int mt = 0; mt < 2; ++mt) {
      bf16x8 bf[4];
#pragma unroll
      for (int c = 0; c < 4; ++c)
        bf[c] = *(const bf16x8*)&Tbuf[64 * w + 16 * c + l15][32 * mt + 8 * lg];
#pragma unroll
      for (int q2 = 0; q2 < 4; ++q2) {
        bf16x8 afr[3];
#pragma unroll
        for (int sA = 0; sA < 3; ++sA)
          if (sA < nA)
            afr[sA] = *(const bf16x8*)&AhP[((((size_t)(sA * 2 + mt) * 4 + q2) * 4 + lg) * 16 + l15) * 8];
#pragma unroll
        for (int c = 0; c < 4; ++c)
#pragma unroll
          for (int sA = 0; sA < 3; ++sA)
            if (sA < nA)
              acc2[q2][c] = __builtin_amdgcn_mfma_f32_16x16x32_bf16(afr[sA], bf[c], acc2[q2][c], 0, 0, 0);
      }
    }
  }

  // epilogue: (acc + bias) * mask, relu -> global
#pragma unroll
  for (int q2 = 0; q2 < 4; ++q2) {
#pragma unroll
    for (int c = 0; c < 4; ++c) {
      int n = 64 * w + 16 * c + l15;
      float bv = biaS[n];
#pragma unroll
      for (int r = 0; r < 4; ++r) {
        int row = 16 * q2 + 4 * lg + r;
        float val = (acc2[q2][c][r] + bv) * maskS[row];
        out[((size_t)b * 64 + row) * 256 + n] = fmaxf(val, 0.0f);
      }
    }
  }
}

// ---------------------------------------------------------------------------
// Fused prep + layer1 + layer2.  63 KB LDS -> 2 blocks/CU.
// ---------------------------------------------------------------------------
__global__ __launch_bounds__(256, 2) void k_fused(
    const float* __restrict__ x, const float* __restrict__ adj,
    const void* __restrict__ mp,
    const float* __restrict__ b1v, const float* __restrict__ b2v,
    const unsigned short* __restrict__ Wg1, const unsigned short* __restrict__ Wg2,
    unsigned long long* __restrict__ nbr, float* __restrict__ maskf,
    float* __restrict__ bufA, float* __restrict__ bufB) {
  __shared__ unsigned short AhP[12288];      // 24.6 KB
  __shared__ float biaS[256];
  __shared__ float maskS[64];
  __shared__ int s_ni, s_nf;
  __shared__ __align__(16) char U[36864];    // union: prep 33.3K / layers 36.9K

  int b = blockIdx.x, tid = threadIdx.x;

  // ===== phase 0: prep =====
  {
    float* adjS = (float*)U;
    float (*AhS)[65] = (float(*)[65])(U + 16384);
    float* dis = (float*)(U + 33024);
    if (tid == 0) { s_ni = 0; s_nf = 0; }
    const float* ab = adj + (size_t)b * 4096;
    for (int i = tid; i < 4096; i += 256) adjS[i] = ab[i];
    {
      const unsigned* wp = (const unsigned*)mp;
      int ni = 0, nf = 0;
      for (int i = tid; i < 2048; i += 256) {
        unsigned v = wp[i];
        if (v > 1u) ni = 1;
        if (v != 0u && v != 0x3f800000u) nf = 1;
      }
      if (ni) atomicOr(&s_ni, 1);
      if (nf) atomicOr(&s_nf, 1);
    }
    biaS[tid] = b1v[tid];
    __syncthreads();
    if (tid < 64) {
      float s = 0.0f;
      unsigned long long m = 0ull;
      for (int j = 0; j < 64; ++j) {
        float v = adjS[j * 64 + tid];          // symmetric
        s += (j == tid) ? (v + 1.0f) : v;
        if (v != 0.0f) m |= (1ull << j);
      }
      dis[tid] = 1.0f / sqrtf(fmaxf(s, 1.0f));
      nbr[b * 64 + tid] = m;
      int fl = s_ni ? (s_nf ? 2 : 1) : 0;
      int i = b * 64 + tid;
      float r;
      if (fl == 0)      r = ((const int*)mp)[i] ? 1.0f : 0.0f;
      else if (fl == 1) r = (((const float*)mp)[i] != 0.0f) ? 1.0f : 0.0f;
      else              r = ((const unsigned char*)mp)[i] ? 1.0f : 0.0f;
      maskS[tid] = r;
      maskf[i] = r;
    }
    __syncthreads();
    for (int i = tid; i < 4096; i += 256) {
      int r = i >> 6, c = i & 63;
      float a = adjS[i] + ((r == c) ? 1.0f : 0.0f);
      AhS[r][c] = (dis[r] * a) * dis[c];
    }
    __syncthreads();
    for (int ch = tid; ch < 1536; ch += 256) {
      int l15v = ch & 15, lgv = (ch >> 4) & 3, q2 = (ch >> 6) & 3, mt = (ch >> 8) & 1, s = ch >> 9;
      bf16x8 hv;
#pragma unroll
      for (int jj = 0; jj < 8; ++jj)
        hv[jj] = (short)planeOf(AhS[16 * q2 + l15v][32 * mt + 8 * lgv + jj], s);
      *(bf16x8*)&AhP[(size_t)ch * 8] = hv;
    }
    __syncthreads();
  }

  // ===== phase 1: layer1 (x -> bufA) =====
  layer_core(x + (size_t)b * 64 * 128, Wg1, AhP, biaS, maskS, bufA, 4, U, b, tid);
  __syncthreads();
  biaS[tid] = b2v[tid];

  // ===== phase 2: layer2 (bufA -> bufB) =====
  layer_core(bufA + (size_t)b * 64 * 256, Wg2, AhP, biaS, maskS, bufB, 8, U, b, tid);
}

// ---------------------------------------------------------------------------
// cdist + softmin + Gumbel-max sampling + per-wave CC/newadj/newx/gp/lab.
// h read directly from global (L2-hot, written by k_fused).  49.9 KB LDS ->
// 3 blocks/CU.  Regular (L2-allocating) output stores.
// ---------------------------------------------------------------------------
__global__ __launch_bounds__(256, 3) void k_cdsp(const float* __restrict__ h,
                                                 const unsigned short* __restrict__ cen3,
                                                 const float* __restrict__ ccbuf,
                                                 const float* __restrict__ maskf,
                                                 const unsigned long long* __restrict__ nbr,
                                                 float* __restrict__ out_newx,
                                                 float* __restrict__ out_newadj,
                                                 float* __restrict__ out_gp,
                                                 float* __restrict__ out_lab) {
  __shared__ float Dred[4][64][36];    // 36.9 KB (reused as newadj bitmap in phase 4)
  __shared__ float hhp[64][4];
  __shared__ float lgp[64][33];
  __shared__ float mxs[64], lgden[64];
  __shared__ int concS[4][64];
  __shared__ float ppS[4][64];
  __shared__ int labFS[4][64];

  int b = blockIdx.x, tid = threadIdx.x;
  int w = tid >> 6, l = tid & 63, l15 = l & 15, lg = l >> 4;
  const float* hb = h + (size_t)b * 16384;

  // hh partials: thread t -> row t&63, f-quarter t>>6 (global reads, L2-hot)
  {
    int row = tid & 63, qt = tid >> 6;
    float s = 0.0f;
    for (int u = 0; u < 16; ++u) {
      float4 v = *(const float4*)&hb[row * 256 + qt * 64 + u * 4];
      float t = fadd_s(fadd_s(fadd_s(fmul_s(v.x, v.x), fmul_s(v.y, v.y)), fmul_s(v.z, v.z)), fmul_s(v.w, v.w));
      s = fadd_s(s, t);
    }
    hhp[row][qt] = s;
  }

  f32x4 acc[4][2];
#pragma unroll
  for (int qt = 0; qt < 4; ++qt)
#pragma unroll
    for (int c = 0; c < 2; ++c) acc[qt][c] = (f32x4){0.f, 0.f, 0.f, 0.f};

#pragma unroll
  for (int ks2 = 0; ks2 < 2; ++ks2) {
    int ks = 2 * w + ks2;
#pragma unroll
    for (int qt = 0; qt < 4; ++qt) {
      int row = 16 * qt + l15;
      float4 v0 = *(const float4*)&hb[row * 256 + 32 * ks + 8 * lg];
      float4 v1 = *(const float4*)&hb[row * 256 + 32 * ks + 8 * lg + 4];
      float vv[8] = {v0.x, v0.y, v0.z, v0.w, v1.x, v1.y, v1.z, v1.w};
      bf16x8 a0, a1, a2;
#pragma unroll
      for (int jj = 0; jj < 8; ++jj) {
        unsigned h1, h2, h3; split3(vv[jj], h1, h2, h3);
        a0[jj] = (short)h1; a1[jj] = (short)h2; a2[jj] = (short)h3;
      }
#pragma unroll
      for (int c = 0; c < 2; ++c) {
        const unsigned short* cb = cen3 + ((size_t)(ks * 2 + c) * 64 + l15 * 4 + lg) * 8;
        bf16x8 b0 = *(const bf16x8*)cb;
        bf16x8 b1 = *(const bf16x8*)(cb + 8192);
        bf16x8 b2 = *(const bf16x8*)(cb + 16384);
        MF6(a0, a1, a2, b0, b1, b2, acc[qt][c]);
      }
    }
  }

#pragma unroll
  for (int qt = 0; qt < 4; ++qt)
#pragma unroll
    for (int c = 0; c < 2; ++c)
#pragma unroll
      for (int r = 0; r < 4; ++r)
        Dred[w][16 * qt + 4 * lg + r][16 * c + l15] = acc[qt][c][r];
  __syncthreads();

  {
    int n = tid >> 2, kq = tid & 3;
    float hh = (hhp[n][0] + hhp[n][1]) + (hhp[n][2] + hhp[n][3]);
#pragma unroll
    for (int j = 0; j < 8; ++j) {
      int k = kq * 8 + j;
      float dot = (Dred[0][n][k] + Dred[1][n][k]) + (Dred[2][n][k] + Dred[3][n][k]);
      float d2 = fsub_s(fadd_s(hh, ccbuf[k]), fmul_s(2.0f, dot));
      lgp[n][k] = -10.0f * sqrtf(fmaxf(d2, 1e-12f));
    }
  }
  __syncthreads();

  if (tid < 64) {
    float mx = -1e30f;
    for (int k = 0; k < 32; ++k) mx = fmaxf(mx, lgp[tid][k]);
    float den = 0.0f;
    for (int k = 0; k < 32; ++k) den += expf(lgp[tid][k] - mx);
    mxs[tid] = mx; lgden[tid] = logf(den);
  }
  __syncthreads();
  for (int p = tid; p < 2048; p += 256) {
    int n = p >> 5, k = p & 31;
    lgp[n][k] = (lgp[n][k] - mxs[n]) - lgden[n];
  }
  __syncthreads();

  {
    int hw = tid >> 5, k = tid & 31;
    for (int pass = 0; pass < 8; ++pass) {
      int n = hw * 8 + pass;
      float lp = lgp[n][k];
#pragma unroll
      for (int s4 = 0; s4 < 4; ++s4) {
        unsigned flat = (unsigned)(s4 * 32768 + b * 64 + n) * 32u + (unsigned)k;
        unsigned bits = tf_bits(flat);
        float fu = __uint_as_float((bits >> 9) | 0x3f800000u) - 1.0f;
        float u = fmaxf(TINYF, fadd_s(fmul_s(fu, 1.0f - TINYF), TINYF));
        float g = -logf(-logf(u));
        float v = lp + g;
        int bi = k;
#pragma unroll
        for (int d = 1; d < 32; d <<= 1) {      // max, first-index ties
          float ov = __shfl_xor(v, d, 32);
          int oi = __shfl_xor(bi, d, 32);
          if (ov > v || (ov == v && oi < bi)) { v = ov; bi = oi; }
        }
        if (k == 0) {
          concS[s4][n] = bi;
          ppS[s4][n] = expf(lgp[n][bi]);
        }
      }
    }
  }
  __syncthreads();

  // ===== phase 4: per-wave (sample = wave) CC + outputs =====
  {
    unsigned char (*o)[4096] = (unsigned char(*)[4096])Dred;
    int s = w, lane = l;
    int sbo = s * 512 + b;
    int c0 = concS[s][lane];
    bool mk = maskf[b * 64 + lane] != 0.0f;
    unsigned long long nb = nbr[b * 64 + lane];
    unsigned long long sm = 0ull;
    {
      unsigned long long t = nb;
      while (t) { int j = __ffsll(t) - 1; if (concS[s][j] == c0) sm |= (1ull << j); t &= t - 1; }
    }
    labFS[s][lane] = lane + 1;                  // wave-lockstep Jacobi fixpoint
    for (int it = 0; it < 64; ++it) {
      int m = labFS[s][lane];
      unsigned long long t = sm;
      while (t) { int j = __ffsll(t) - 1; m = min(m, labFS[s][j]); t &= t - 1; }
      bool ch = m < labFS[s][lane];
      if (ch) labFS[s][lane] = m;
      if (!__any(ch)) break;
    }
    int lf = mk ? labFS[s][lane] : 0;
    out_lab[(size_t)sbo * 64 + lane] = (float)lf;
    float pv = mk ? ppS[s][lane] : 1.0f;
#pragma unroll
    for (int d = 1; d < 64; d <<= 1) pv *= __shfl_xor(pv, d, 64);
    if (lane == 0) out_gp[sbo] = pv;
    labFS[s][lane] = lf;                        // final masked labels (lockstep)
    unsigned long long cm = 0ull;
    for (int j = 0; j < 64; ++j)
      if (labFS[s][j] == lane + 1) cm |= (1ull << j);
    // pooled adjacency (byte bitmap per sample)
    {
      unsigned* op = (unsigned*)o[s];
#pragma unroll
      for (int u = 0; u < 16; ++u) op[u * 64 + lane] = 0u;
      if (lf > 0) {
        unsigned long long t = nb;
        while (t) {
          int j = __ffsll(t) - 1; t &= t - 1;
          int lj = labFS[s][j];
          if (lj > 0) o[s][(lf - 1) * 64 + (lj - 1)] = 1;
        }
      }
      float* dA = out_newadj + (size_t)sbo * 4096;
#pragma unroll
      for (int u = 0; u < 16; ++u) {
        int base = u * 256 + lane * 4;
        fx4 v;
        v.x = o[s][base + 0] ? 1.0f : 0.0f;
        v.y = o[s][base + 1] ? 1.0f : 0.0f;
        v.z = o[s][base + 2] ? 1.0f : 0.0f;
        v.w = o[s][base + 3] ? 1.0f : 0.0f;
        *(fx4*)&dA[base] = v;
      }
    }
    // scatter-mean new_x from global h (coalesced 1 KB lines, L2-hot)
    float* dX = out_newx + (size_t)sbo * 16384;
    for (int c = 0; c < 64; ++c) {
      unsigned long long m = __shfl(cm, c, 64);
      float4 acc4 = make_float4(0.f, 0.f, 0.f, 0.f);
      unsigned long long t = m;
      while (t) {
        int j = __ffsll(t) - 1; t &= t - 1;
        float4 v = *(const float4*)&hb[j * 256 + lane * 4];
        acc4.x += v.x; acc4.y += v.y; acc4.z += v.z; acc4.w += v.w;
      }
      int cnt = __popcll(m);
      float cf = (float)(cnt > 0 ? cnt : 1);
      fx4 r;
      r.x = acc4.x / cf; r.y = acc4.y / cf; r.z = acc4.z / cf; r.w = acc4.w / cf;
      *(fx4*)&dX[(size_t)c * 256 + lane * 4] = r;
    }
  }
}

// ---------------------------------------------------------------------------
extern "C" void kernel_launch(void* const* d_in, const int* in_sizes, int n_in,
                              void* d_out, int out_size, void* d_ws, size_t ws_size,
                              hipStream_t stream) {
  (void)in_sizes; (void)n_in; (void)out_size; (void)ws_size;
  const float* x   = (const float*)d_in[0];
  const float* adj = (const float*)d_in[1];
  const void*  mp  = d_in[2];
  const float* W1  = (const float*)d_in[3];
  const float* b1  = (const float*)d_in[4];
  const float* W2  = (const float*)d_in[5];
  const float* b2  = (const float*)d_in[6];
  const float* cen = (const float*)d_in[7];

  char* ws = (char*)d_ws;
  unsigned short* Wg1  = (unsigned short*)(ws + 0);          // 196,608
  unsigned short* Wg2  = (unsigned short*)(ws + 196608);     // 393,216
  unsigned short* cen3 = (unsigned short*)(ws + 589824);     // 49,152
  float* ccbuf         = (float*)(ws + 638976);              // 128
  unsigned long long* nbr = (unsigned long long*)(ws + 655360);  // 262,144
  float* maskf         = (float*)(ws + 917504);              // 131,072
  float* bufA          = (float*)(ws + 2097152);             // 33,554,432 (h1)
  float* bufB          = (float*)(ws + 37748736);            // 33,554,432 (h)

  float* out        = (float*)d_out;
  float* out_newx   = out;                 // 2048*64*256
  float* out_newadj = out + 33554432;      // 2048*64*64
  float* out_gp     = out + 41943040;      // 2048
  float* out_lab    = out + 41945088;      // 2048*64

  hipLaunchKernelGGL(k_setup, dim3(148), dim3(256), 0, stream, W1, W2, cen, Wg1, Wg2, cen3, ccbuf);
  hipLaunchKernelGGL(k_fused, dim3(512), dim3(256), 0, stream, x, adj, mp, b1, b2,
                     Wg1, Wg2, nbr, maskf, bufA, bufB);
  hipLaunchKernelGGL(k_cdsp,  dim3(512), dim3(256), 0, stream, bufB, cen3, ccbuf, maskf, nbr,
                     out_newx, out_newadj, out_gp, out_lab);
}

// Round 14
// 147.636 us; speedup vs baseline: 1.0429x; 1.0082x over previous
//
#include <hip/hip_runtime.h>

#define B_    512

static constexpr float TINYF = 1.17549435e-38f;
typedef float fx4  __attribute__((ext_vector_type(4)));
typedef short bf16x8 __attribute__((ext_vector_type(8)));
typedef float f32x4 __attribute__((ext_vector_type(4)));
typedef unsigned short u16x4 __attribute__((ext_vector_type(4)));

// Contraction-pinned fp32 ops (RN, no fma fusion possible across these).
__device__ __forceinline__ float fmul_s(float a, float b) { float r; asm("v_mul_f32 %0, %1, %2" : "=v"(r) : "v"(a), "v"(b)); return r; }
__device__ __forceinline__ float fadd_s(float a, float b) { float r; asm("v_add_f32 %0, %1, %2" : "=v"(r) : "v"(a), "v"(b)); return r; }
__device__ __forceinline__ float fsub_s(float a, float b) { float r; asm("v_sub_f32 %0, %1, %2" : "=v"(r) : "v"(a), "v"(b)); return r; }

// ---------------------------------------------------------------------------
// Threefry-2x32, key = (0, 42), partitionable path.
// ---------------------------------------------------------------------------
__device__ __forceinline__ unsigned tf_bits(unsigned lo) {
  const unsigned ks0 = 0u, ks1 = 42u, ks2 = 0x1BD11BF0u;
  unsigned x0 = 0u + ks0;
  unsigned x1 = lo + ks1;
#define TFR(r) { x0 += x1; x1 = (x1 << r) | (x1 >> (32 - r)); x1 ^= x0; }
  TFR(13) TFR(15) TFR(26) TFR(6)
  x0 += ks1; x1 += ks2 + 1u;
  TFR(17) TFR(29) TFR(16) TFR(24)
  x0 += ks2; x1 += ks0 + 2u;
  TFR(13) TFR(15) TFR(26) TFR(6)
  x0 += ks0; x1 += ks1 + 3u;
  TFR(17) TFR(29) TFR(16) TFR(24)
  x0 += ks1; x1 += ks2 + 4u;
  TFR(13) TFR(15) TFR(26) TFR(6)
  x0 += ks2; x1 += ks0 + 5u;
#undef TFR
  return x0 ^ x1;
}

// Exact fp32 -> 3x bf16 split (truncation)
__device__ __forceinline__ void split3(float v, unsigned& b1, unsigned& b2, unsigned& b3) {
  unsigned u1 = __float_as_uint(v) & 0xFFFF0000u;
  float r1 = v - __uint_as_float(u1);
  unsigned u2 = __float_as_uint(r1) & 0xFFFF0000u;
  float r2 = r1 - __uint_as_float(u2);
  unsigned u3 = __float_as_uint(r2) & 0xFFFF0000u;
  b1 = u1 >> 16; b2 = u2 >> 16; b3 = u3 >> 16;
}

__device__ __forceinline__ unsigned short planeOf(float v, int s) {
  unsigned u1 = __float_as_uint(v) & 0xFFFF0000u;
  if (s == 0) return (unsigned short)(u1 >> 16);
  float r1 = v - __uint_as_float(u1);
  unsigned u2 = __float_as_uint(r1) & 0xFFFF0000u;
  if (s == 1) return (unsigned short)(u2 >> 16);
  float r2 = r1 - __uint_as_float(u2);
  return (unsigned short)((__float_as_uint(r2) & 0xFFFF0000u) >> 16);
}

// 6-product split accumulation (drops terms <= 2^-27 relative)
#define MF6(A0, A1, A2, Bv0, Bv1, Bv2, ACC)                                   \
  ACC = __builtin_amdgcn_mfma_f32_16x16x32_bf16(A0, Bv0, ACC, 0, 0, 0);       \
  ACC = __builtin_amdgcn_mfma_f32_16x16x32_bf16(A0, Bv1, ACC, 0, 0, 0);       \
  ACC = __builtin_amdgcn_mfma_f32_16x16x32_bf16(A1, Bv0, ACC, 0, 0, 0);       \
  ACC = __builtin_amdgcn_mfma_f32_16x16x32_bf16(A0, Bv2, ACC, 0, 0, 0);       \
  ACC = __builtin_amdgcn_mfma_f32_16x16x32_bf16(A1, Bv1, ACC, 0, 0, 0);       \
  ACC = __builtin_amdgcn_mfma_f32_16x16x32_bf16(A2, Bv0, ACC, 0, 0, 0);

// ---------------------------------------------------------------------------
// Setup: W1/W2 split planes, centroid norms (FMA-pinned: matches default
// -O3 contraction of s += v*v, now source-defined), centroid split planes.
// ---------------------------------------------------------------------------
__global__ void k_setup(const float* __restrict__ W1, const float* __restrict__ W2,
                        const float* __restrict__ cen,
                        unsigned short* __restrict__ Wg1, unsigned short* __restrict__ Wg2,
                        unsigned short* __restrict__ cen3, float* __restrict__ ccbuf) {
  int bi = blockIdx.x, tid = threadIdx.x;
  if (bi < 144) {
    const float* W; unsigned short* Wg; int nk, s, ks, g;
    if (bi < 48) { W = W1; Wg = Wg1; nk = 4; s = bi >> 4; ks = (bi >> 2) & 3; g = bi & 3; }
    else { int t = bi - 48; W = W2; Wg = Wg2; nk = 8; s = t >> 5; ks = (t >> 2) & 7; g = t & 3; }
    int n = tid;
    bf16x8 hv;
#pragma unroll
    for (int jj = 0; jj < 8; ++jj) {
      float v = W[(size_t)(ks * 32 + g * 8 + jj) * 256 + n];
      hv[jj] = (short)planeOf(v, s);
    }
    *(bf16x8*)&Wg[((((size_t)s * nk + ks) * 4 + g) * 256 + n) * 8] = hv;
  } else if (bi == 144) {
    int k = tid >> 3, l8 = tid & 7;
    float s = 0.0f;
    for (int m = 0; m < 32; ++m) { float v = cen[k * 256 + l8 + 8 * m]; s = __builtin_fmaf(v, v, s); }
#pragma unroll
    for (int d = 1; d < 8; d <<= 1) s += __shfl_xor(s, d, 64);
    if (l8 == 0) ccbuf[k] = s;
  } else {
    int s = bi - 145;
    for (int u = 0; u < 4; ++u) {
      int idx = tid + 256 * u;
      int ks = idx >> 7, c = (idx >> 6) & 1, rem = idx & 63;
      int l15v = rem >> 2, lgv = rem & 3;
      bf16x8 hv;
#pragma unroll
      for (int jj = 0; jj < 8; ++jj)
        hv[jj] = (short)planeOf(cen[(size_t)(16 * c + l15v) * 256 + 32 * ks + 8 * lgv + jj], s);
      *(bf16x8*)&cen3[(size_t)s * 8192 + (size_t)idx * 8] = hv;
    }
  }
}

// ---------------------------------------------------------------------------
// Layer core (global->global): out = relu(maskS * (Ahat @ (A @ W) + biaS)).
// GEMM#2's Tbuf is wave-local -> no barriers in the sB loop.
// ---------------------------------------------------------------------------
__device__ __forceinline__ void layer_core(const float* __restrict__ A,
                                           const unsigned short* __restrict__ Wg,
                                           const unsigned short* AhP,
                                           const float* biaS, const float* maskS,
                                           float* __restrict__ out, int nk,
                                           char* U, int b, int tid) {
  unsigned short (*Ap)[3][2112] = (unsigned short(*)[3][2112])U;  // [2][3][2112]
  unsigned short (*Tbuf)[72]    = (unsigned short(*)[72])U;       // [256][72]
  int w = tid >> 6, l = tid & 63;
  int l15 = l & 15, lg = l >> 4;
  int K = nk * 32;
  int srow = tid >> 2, sg = tid & 3;
  const float* sp = A + (size_t)srow * K + sg * 8;

  // stage K-step 0 into buffer 0
  {
    float4 v0 = *(const float4*)(sp);
    float4 v1 = *(const float4*)(sp + 4);
    float vv[8] = {v0.x, v0.y, v0.z, v0.w, v1.x, v1.y, v1.z, v1.w};
    bf16x8 p1, p2, p3;
#pragma unroll
    for (int jj = 0; jj < 8; ++jj) {
      unsigned h1, h2, h3; split3(vv[jj], h1, h2, h3);
      p1[jj] = (short)h1; p2[jj] = (short)h2; p3[jj] = (short)h3;
    }
    int off = sg * 528 + srow * 8;
    *(bf16x8*)&Ap[0][0][off] = p1;
    *(bf16x8*)&Ap[0][1][off] = p2;
    *(bf16x8*)&Ap[0][2][off] = p3;
  }
  __syncthreads();

  f32x4 acc1[4][4];
#pragma unroll
  for (int q = 0; q < 4; ++q)
#pragma unroll
    for (int c = 0; c < 4; ++c) acc1[q][c] = (f32x4){0.f, 0.f, 0.f, 0.f};

  const size_t wss = (size_t)nk * 8192;

  for (int ks = 0; ks < nk; ++ks) {
    int cur = ks & 1;
    float4 v0, v1;
    bool pf = (ks + 1 < nk);
    if (pf) {
      v0 = *(const float4*)(sp + (ks + 1) * 32);
      v1 = *(const float4*)(sp + (ks + 1) * 32 + 4);
    }
    bf16x8 af[4][3];
#pragma unroll
    for (int q = 0; q < 4; ++q) {
      int off = lg * 528 + (16 * q + l15) * 8;
#pragma unroll
      for (int s = 0; s < 3; ++s) af[q][s] = *(const bf16x8*)&Ap[cur][s][off];
    }
#pragma unroll
    for (int c = 0; c < 4; ++c) {
      size_t wbase = (((size_t)ks * 4 + lg) * 256 + (64 * w + 16 * c + l15)) * 8;
      bf16x8 b0 = *(const bf16x8*)&Wg[wbase];
      bf16x8 b1 = *(const bf16x8*)&Wg[wbase + wss];
      bf16x8 b2 = *(const bf16x8*)&Wg[wbase + 2 * wss];
#pragma unroll
      for (int q = 0; q < 4; ++q) {
        MF6(af[q][0], af[q][1], af[q][2], b0, b1, b2, acc1[q][c]);
      }
    }
    if (pf) {
      float vv[8] = {v0.x, v0.y, v0.z, v0.w, v1.x, v1.y, v1.z, v1.w};
      bf16x8 p1, p2, p3;
#pragma unroll
      for (int jj = 0; jj < 8; ++jj) {
        unsigned h1, h2, h3; split3(vv[jj], h1, h2, h3);
        p1[jj] = (short)h1; p2[jj] = (short)h2; p3[jj] = (short)h3;
      }
      int off = sg * 528 + srow * 8;
      *(bf16x8*)&Ap[cur ^ 1][0][off] = p1;
      *(bf16x8*)&Ap[cur ^ 1][1][off] = p2;
      *(bf16x8*)&Ap[cur ^ 1][2][off] = p3;
    }
    __syncthreads();
  }

  // GEMM#2 phased over T split-planes sB; product budget nA = 3 - sB.
  f32x4 acc2[4][4];
#pragma unroll
  for (int q = 0; q < 4; ++q)
#pragma unroll
    for (int c = 0; c < 4; ++c) acc2[q][c] = (f32x4){0.f, 0.f, 0.f, 0.f};

#pragma unroll
  for (int sB = 0; sB < 3; ++sB) {
    const int nA = 3 - sB;
#pragma unroll
    for (int q = 0; q < 4; ++q)
#pragma unroll
      for (int c = 0; c < 4; ++c) {
        u16x4 pv;
#pragma unroll
        for (int r = 0; r < 4; ++r) pv[r] = planeOf(acc1[q][c][r], sB);
        *(u16x4*)&Tbuf[64 * w + 16 * c + l15][16 * q + 4 * lg] = pv;
      }
#pragma unroll
    for (int mt = 0; mt < 2; ++mt) {
      bf16x8 bf[4];
#pragma unroll
      for (int c = 0; c < 4; ++c)
        bf[c] = *(const bf16x8*)&Tbuf[64 * w + 16 * c + l15][32 * mt + 8 * lg];
#pragma unroll
      for (int q2 = 0; q2 < 4; ++q2) {
        bf16x8 afr[3];
#pragma unroll
        for (int sA = 0; sA < 3; ++sA)
          if (sA < nA)
            afr[sA] = *(const bf16x8*)&AhP[((((size_t)(sA * 2 + mt) * 4 + q2) * 4 + lg) * 16 + l15) * 8];
#pragma unroll
        for (int c = 0; c < 4; ++c)
#pragma unroll
          for (int sA = 0; sA < 3; ++sA)
            if (sA < nA)
              acc2[q2][c] = __builtin_amdgcn_mfma_f32_16x16x32_bf16(afr[sA], bf[c], acc2[q2][c], 0, 0, 0);
      }
    }
  }

  // epilogue: (acc + bias) * mask, relu -> global
#pragma unroll
  for (int q2 = 0; q2 < 4; ++q2) {
#pragma unroll
    for (int c = 0; c < 4; ++c) {
      int n = 64 * w + 16 * c + l15;
      float bv = biaS[n];
#pragma unroll
      for (int r = 0; r < 4; ++r) {
        int row = 16 * q2 + 4 * lg + r;
        float val = (acc2[q2][c][r] + bv) * maskS[row];
        out[((size_t)b * 64 + row) * 256 + n] = fmaxf(val, 0.0f);
      }
    }
  }
}

// ---------------------------------------------------------------------------
// Fused prep + layer1 + layer2.  63 KB LDS -> 2 blocks/CU.
// ---------------------------------------------------------------------------
__global__ __launch_bounds__(256, 2) void k_fused(
    const float* __restrict__ x, const float* __restrict__ adj,
    const void* __restrict__ mp,
    const float* __restrict__ b1v, const float* __restrict__ b2v,
    const unsigned short* __restrict__ Wg1, const unsigned short* __restrict__ Wg2,
    unsigned long long* __restrict__ nbr, float* __restrict__ maskf,
    float* __restrict__ bufA, float* __restrict__ bufB) {
  __shared__ unsigned short AhP[12288];      // 24.6 KB
  __shared__ float biaS[256];
  __shared__ float maskS[64];
  __shared__ int s_ni, s_nf;
  __shared__ __align__(16) char U[36864];    // union: prep 33.3K / layers 36.9K

  int b = blockIdx.x, tid = threadIdx.x;

  // ===== phase 0: prep =====
  {
    float* adjS = (float*)U;
    float (*AhS)[65] = (float(*)[65])(U + 16384);
    float* dis = (float*)(U + 33024);
    if (tid == 0) { s_ni = 0; s_nf = 0; }
    const float* ab = adj + (size_t)b * 4096;
    for (int i = tid; i < 4096; i += 256) adjS[i] = ab[i];
    {
      const unsigned* wp = (const unsigned*)mp;
      int ni = 0, nf = 0;
      for (int i = tid; i < 2048; i += 256) {
        unsigned v = wp[i];
        if (v > 1u) ni = 1;
        if (v != 0u && v != 0x3f800000u) nf = 1;
      }
      if (ni) atomicOr(&s_ni, 1);
      if (nf) atomicOr(&s_nf, 1);
    }
    biaS[tid] = b1v[tid];
    __syncthreads();
    if (tid < 64) {
      float s = 0.0f;
      unsigned long long m = 0ull;
      for (int j = 0; j < 64; ++j) {
        float v = adjS[j * 64 + tid];          // symmetric
        s += (j == tid) ? (v + 1.0f) : v;
        if (v != 0.0f) m |= (1ull << j);
      }
      dis[tid] = 1.0f / sqrtf(fmaxf(s, 1.0f));
      nbr[b * 64 + tid] = m;
      int fl = s_ni ? (s_nf ? 2 : 1) : 0;
      int i = b * 64 + tid;
      float r;
      if (fl == 0)      r = ((const int*)mp)[i] ? 1.0f : 0.0f;
      else if (fl == 1) r = (((const float*)mp)[i] != 0.0f) ? 1.0f : 0.0f;
      else              r = ((const unsigned char*)mp)[i] ? 1.0f : 0.0f;
      maskS[tid] = r;
      maskf[i] = r;
    }
    __syncthreads();
    for (int i = tid; i < 4096; i += 256) {
      int r = i >> 6, c = i & 63;
      float a = adjS[i] + ((r == c) ? 1.0f : 0.0f);
      AhS[r][c] = (dis[r] * a) * dis[c];
    }
    __syncthreads();
    for (int ch = tid; ch < 1536; ch += 256) {
      int l15v = ch & 15, lgv = (ch >> 4) & 3, q2 = (ch >> 6) & 3, mt = (ch >> 8) & 1, s = ch >> 9;
      bf16x8 hv;
#pragma unroll
      for (int jj = 0; jj < 8; ++jj)
        hv[jj] = (short)planeOf(AhS[16 * q2 + l15v][32 * mt + 8 * lgv + jj], s);
      *(bf16x8*)&AhP[(size_t)ch * 8] = hv;
    }
    __syncthreads();
  }

  // ===== phase 1: layer1 (x -> bufA) =====
  layer_core(x + (size_t)b * 64 * 128, Wg1, AhP, biaS, maskS, bufA, 4, U, b, tid);
  __syncthreads();
  biaS[tid] = b2v[tid];

  // ===== phase 2: layer2 (bufA -> bufB) =====
  layer_core(bufA + (size_t)b * 64 * 256, Wg2, AhP, biaS, maskS, bufB, 8, U, b, tid);
}

// ---------------------------------------------------------------------------
// cdist + softmin + Gumbel-max sampling + per-wave CC/newadj/newx/gp/lab.
// LDS diet via phase-disjoint aliasing into one 37.9 KB arena:
//   [0,36864)      Dred[4][64][36]   (GEMM partials; logits phase)
//   [0,9216)       lgp[64][36]       = Dred[0] (element-exclusive overwrite)
//   [16384,17408)  concS[4][64]      (written in sampling; Dred[1] dead)
//   [17408,18432)  ppS[4][64]
//   [18432,19456)  labFS[4][64]      (phase 4; Dred[2] dead)
//   [0,16384)      o[4][4096] bytes  (phase 4; lgp dead)
//   [36864,37888)  hhp[64][4] -> mxs/lgden after logits phase
// 37.9 KB -> 4 blocks/CU at __launch_bounds__(256,4).  No fp-op changes.
// ---------------------------------------------------------------------------
__global__ __launch_bounds__(256, 4) void k_cdsp(const float* __restrict__ h,
                                                 const unsigned short* __restrict__ cen3,
                                                 const float* __restrict__ ccbuf,
                                                 const float* __restrict__ maskf,
                                                 const unsigned long long* __restrict__ nbr,
                                                 float* __restrict__ out_newx,
                                                 float* __restrict__ out_newadj,
                                                 float* __restrict__ out_gp,
                                                 float* __restrict__ out_lab) {
  __shared__ __align__(16) char SM[37888];
  float (*Dred)[64][36] = (float(*)[64][36])SM;
  float (*hhp)[4]       = (float(*)[4])(SM + 36864);
  float (*lgp)[36]      = (float(*)[36])SM;            // alias Dred[0]
  float* mxs            = (float*)(SM + 36864);        // alias hhp (dead)
  float* lgden          = (float*)(SM + 36864 + 256);
  int   (*concS)[64]    = (int(*)[64])(SM + 16384);    // Dred[1] tail (dead)
  float (*ppS)[64]      = (float(*)[64])(SM + 17408);
  int   (*labFS)[64]    = (int(*)[64])(SM + 18432);    // Dred[2] head (dead)

  int b = blockIdx.x, tid = threadIdx.x;
  int w = tid >> 6, l = tid & 63, l15 = l & 15, lg = l >> 4;
  const float* hb = h + (size_t)b * 16384;

  // hh partials: thread t -> row t&63, f-quarter t>>6 (global reads, L2-hot)
  {
    int row = tid & 63, qt = tid >> 6;
    float s = 0.0f;
    for (int u = 0; u < 16; ++u) {
      float4 v = *(const float4*)&hb[row * 256 + qt * 64 + u * 4];
      float t = fadd_s(fadd_s(fadd_s(fmul_s(v.x, v.x), fmul_s(v.y, v.y)), fmul_s(v.z, v.z)), fmul_s(v.w, v.w));
      s = fadd_s(s, t);
    }
    hhp[row][qt] = s;
  }

  f32x4 acc[4][2];
#pragma unroll
  for (int qt = 0; qt < 4; ++qt)
#pragma unroll
    for (int c = 0; c < 2; ++c) acc[qt][c] = (f32x4){0.f, 0.f, 0.f, 0.f};

#pragma unroll
  for (int ks2 = 0; ks2 < 2; ++ks2) {
    int ks = 2 * w + ks2;
#pragma unroll
    for (int qt = 0; qt < 4; ++qt) {
      int row = 16 * qt + l15;
      float4 v0 = *(const float4*)&hb[row * 256 + 32 * ks + 8 * lg];
      float4 v1 = *(const float4*)&hb[row * 256 + 32 * ks + 8 * lg + 4];
      float vv[8] = {v0.x, v0.y, v0.z, v0.w, v1.x, v1.y, v1.z, v1.w};
      bf16x8 a0, a1, a2;
#pragma unroll
      for (int jj = 0; jj < 8; ++jj) {
        unsigned h1, h2, h3; split3(vv[jj], h1, h2, h3);
        a0[jj] = (short)h1; a1[jj] = (short)h2; a2[jj] = (short)h3;
      }
#pragma unroll
      for (int c = 0; c < 2; ++c) {
        const unsigned short* cb = cen3 + ((size_t)(ks * 2 + c) * 64 + l15 * 4 + lg) * 8;
        bf16x8 b0 = *(const bf16x8*)cb;
        bf16x8 b1 = *(const bf16x8*)(cb + 8192);
        bf16x8 b2 = *(const bf16x8*)(cb + 16384);
        MF6(a0, a1, a2, b0, b1, b2, acc[qt][c]);
      }
    }
  }

#pragma unroll
  for (int qt = 0; qt < 4; ++qt)
#pragma unroll
    for (int c = 0; c < 2; ++c)
#pragma unroll
      for (int r = 0; r < 4; ++r)
        Dred[w][16 * qt + 4 * lg + r][16 * c + l15] = acc[qt][c][r];
  __syncthreads();

  // logits: thread (n = tid>>2, kq = tid&3) owns (n, k in [8kq, 8kq+8));
  // writes lgp[n][k] == Dred[0][n][k] AFTER its own read of that element.
  {
    int n = tid >> 2, kq = tid & 3;
    float hh = (hhp[n][0] + hhp[n][1]) + (hhp[n][2] + hhp[n][3]);
#pragma unroll
    for (int j = 0; j < 8; ++j) {
      int k = kq * 8 + j;
      float dot = (Dred[0][n][k] + Dred[1][n][k]) + (Dred[2][n][k] + Dred[3][n][k]);
      float d2 = fsub_s(fadd_s(hh, ccbuf[k]), fmul_s(2.0f, dot));
      lgp[n][k] = -10.0f * sqrtf(fmaxf(d2, 1e-12f));
    }
  }
  __syncthreads();

  if (tid < 64) {
    float mx = -1e30f;
    for (int k = 0; k < 32; ++k) mx = fmaxf(mx, lgp[tid][k]);
    float den = 0.0f;
    for (int k = 0; k < 32; ++k) den += expf(lgp[tid][k] - mx);
    mxs[tid] = mx; lgden[tid] = logf(den);
  }
  __syncthreads();
  for (int p = tid; p < 2048; p += 256) {
    int n = p >> 5, k = p & 31;
    lgp[n][k] = (lgp[n][k] - mxs[n]) - lgden[n];
  }
  __syncthreads();

  {
    int hw = tid >> 5, k = tid & 31;
    for (int pass = 0; pass < 8; ++pass) {
      int n = hw * 8 + pass;
      float lp = lgp[n][k];
#pragma unroll
      for (int s4 = 0; s4 < 4; ++s4) {
        unsigned flat = (unsigned)(s4 * 32768 + b * 64 + n) * 32u + (unsigned)k;
        unsigned bits = tf_bits(flat);
        float fu = __uint_as_float((bits >> 9) | 0x3f800000u) - 1.0f;
        float u = fmaxf(TINYF, fadd_s(fmul_s(fu, 1.0f - TINYF), TINYF));
        float g = -logf(-logf(u));
        float v = lp + g;
        int bi = k;
#pragma unroll
        for (int d = 1; d < 32; d <<= 1) {      // max, first-index ties
          float ov = __shfl_xor(v, d, 32);
          int oi = __shfl_xor(bi, d, 32);
          if (ov > v || (ov == v && oi < bi)) { v = ov; bi = oi; }
        }
        if (k == 0) {
          concS[s4][n] = bi;
          ppS[s4][n] = expf(lgp[n][bi]);
        }
      }
    }
  }
  __syncthreads();

  // ===== phase 4: per-wave (sample = wave) CC + outputs =====
  {
    unsigned char (*o)[4096] = (unsigned char(*)[4096])SM;   // lgp dead
    int s = w, lane = l;
    int sbo = s * 512 + b;
    int c0 = concS[s][lane];
    bool mk = maskf[b * 64 + lane] != 0.0f;
    unsigned long long nb = nbr[b * 64 + lane];
    unsigned long long sm = 0ull;
    {
      unsigned long long t = nb;
      while (t) { int j = __ffsll(t) - 1; if (concS[s][j] == c0) sm |= (1ull << j); t &= t - 1; }
    }
    labFS[s][lane] = lane + 1;                  // wave-lockstep Jacobi fixpoint
    for (int it = 0; it < 64; ++it) {
      int m = labFS[s][lane];
      unsigned long long t = sm;
      while (t) { int j = __ffsll(t) - 1; m = min(m, labFS[s][j]); t &= t - 1; }
      bool ch = m < labFS[s][lane];
      if (ch) labFS[s][lane] = m;
      if (!__any(ch)) break;
    }
    int lf = mk ? labFS[s][lane] : 0;
    out_lab[(size_t)sbo * 64 + lane] = (float)lf;
    float pv = mk ? ppS[s][lane] : 1.0f;
#pragma unroll
    for (int d = 1; d < 64; d <<= 1) pv *= __shfl_xor(pv, d, 64);
    if (lane == 0) out_gp[sbo] = pv;
    labFS[s][lane] = lf;                        // final masked labels (lockstep)
    unsigned long long cm = 0ull;
    for (int j = 0; j < 64; ++j)
      if (labFS[s][j] == lane + 1) cm |= (1ull << j);
    // pooled adjacency (byte bitmap per sample)
    {
      unsigned* op = (unsigned*)o[s];
#pragma unroll
      for (int u = 0; u < 16; ++u) op[u * 64 + lane] = 0u;
      if (lf > 0) {
        unsigned long long t = nb;
        while (t) {
          int j = __ffsll(t) - 1; t &= t - 1;
          int lj = labFS[s][j];
          if (lj > 0) o[s][(lf - 1) * 64 + (lj - 1)] = 1;
        }
      }
      float* dA = out_newadj + (size_t)sbo * 4096;
#pragma unroll
      for (int u = 0; u < 16; ++u) {
        int base = u * 256 + lane * 4;
        fx4 v;
        v.x = o[s][base + 0] ? 1.0f : 0.0f;
        v.y = o[s][base + 1] ? 1.0f : 0.0f;
        v.z = o[s][base + 2] ? 1.0f : 0.0f;
        v.w = o[s][base + 3] ? 1.0f : 0.0f;
        *(fx4*)&dA[base] = v;
      }
    }
    // scatter-mean new_x from global h (coalesced 1 KB lines, L2-hot)
    float* dX = out_newx + (size_t)sbo * 16384;
    for (int c = 0; c < 64; ++c) {
      unsigned long long m = __shfl(cm, c, 64);
      float4 acc4 = make_float4(0.f, 0.f, 0.f, 0.f);
      unsigned long long t = m;
      while (t) {
        int j = __ffsll(t) - 1; t &= t - 1;
        float4 v = *(const float4*)&hb[j * 256 + lane * 4];
        acc4.x += v.x; acc4.y += v.y; acc4.z += v.z; acc4.w += v.w;
      }
      int cnt = __popcll(m);
      float cf = (float)(cnt > 0 ? cnt : 1);
      fx4 r;
      r.x = acc4.x / cf; r.y = acc4.y / cf; r.z = acc4.z / cf; r.w = acc4.w / cf;
      *(fx4*)&dX[(size_t)c * 256 + lane * 4] = r;
    }
  }
}

// ---------------------------------------------------------------------------
extern "C" void kernel_launch(void* const* d_in, const int* in_sizes, int n_in,
                              void* d_out, int out_size, void* d_ws, size_t ws_size,
                              hipStream_t stream) {
  (void)in_sizes; (void)n_in; (void)out_size; (void)ws_size;
  const float* x   = (const float*)d_in[0];
  const float* adj = (const float*)d_in[1];
  const void*  mp  = d_in[2];
  const float* W1  = (const float*)d_in[3];
  const float* b1  = (const float*)d_in[4];
  const float* W2  = (const float*)d_in[5];
  const float* b2  = (const float*)d_in[6];
  const float* cen = (const float*)d_in[7];

  char* ws = (char*)d_ws;
  unsigned short* Wg1  = (unsigned short*)(ws + 0);          // 196,608
  unsigned short* Wg2  = (unsigned short*)(ws + 196608);     // 393,216
  unsigned short* cen3 = (unsigned short*)(ws + 589824);     // 49,152
  float* ccbuf         = (float*)(ws + 638976);              // 128
  unsigned long long* nbr = (unsigned long long*)(ws + 655360);  // 262,144
  float* maskf         = (float*)(ws + 917504);              // 131,072
  float* bufA          = (float*)(ws + 2097152);             // 33,554,432 (h1)
  float* bufB          = (float*)(ws + 37748736);            // 33,554,432 (h)

  float* out        = (float*)d_out;
  float* out_newx   = out;                 // 2048*64*256
  float* out_newadj = out + 33554432;      // 2048*64*64
  float* out_gp     = out + 41943040;      // 2048
  float* out_lab    = out + 41945088;      // 2048*64

  hipLaunchKernelGGL(k_setup, dim3(148), dim3(256), 0, stream, W1, W2, cen, Wg1, Wg2, cen3, ccbuf);
  hipLaunchKernelGGL(k_fused, dim3(512), dim3(256), 0, stream, x, adj, mp, b1, b2,
                     Wg1, Wg2, nbr, maskf, bufA, bufB);
  hipLaunchKernelGGL(k_cdsp,  dim3(512), dim3(256), 0, stream, bufB, cen3, ccbuf, maskf, nbr,
                     out_newx, out_newadj, out_gp, out_lab);
}